// Round 1
// baseline (7633.827 us; speedup 1.0000x reference)
//
#include <hip/hip_runtime.h>

typedef float v4f __attribute__((ext_vector_type(4)));

namespace {

constexpr int NU = 20000;
constexpr int NT = 50000;
constexpr int NV = 100000;
constexpr int HD = 128;
constexpr int LAYERS = 8;
constexpr float EPS = 1e-5f;

__device__ __forceinline__ float wave_sum(float v) {
#pragma unroll
    for (int m = 32; m >= 1; m >>= 1) v += __shfl_xor(v, m, 64);
    return v;
}

// ---------------- CSR build (per edge type, grouped by destination) ----------------

__global__ void hist_kernel(const int* __restrict__ dst, int* __restrict__ deg, int E) {
    int e = blockIdx.x * blockDim.x + threadIdx.x;
    if (e < E) atomicAdd(&deg[dst[e]], 1);
}

__global__ __launch_bounds__(1024) void scan_kernel(int* __restrict__ deg_cursor,
                                                    int* __restrict__ rowptr,
                                                    float* __restrict__ inv, int n) {
    __shared__ int sums[1024];
    const int t = threadIdx.x;
    const int chunk = (n + 1023) / 1024;
    const int start = min(t * chunk, n);
    const int end = min(start + chunk, n);
    int s = 0;
    for (int i = start; i < end; ++i) s += deg_cursor[i];
    sums[t] = s;
    __syncthreads();
    for (int off = 1; off < 1024; off <<= 1) {
        int v = (t >= off) ? sums[t - off] : 0;
        __syncthreads();
        sums[t] += v;
        __syncthreads();
    }
    int run = (t == 0) ? 0 : sums[t - 1];
    for (int i = start; i < end; ++i) {
        int d = deg_cursor[i];
        rowptr[i] = run;
        inv[i] = 1.0f / (float)max(d, 1);   // mean = sum / max(cnt,1)
        deg_cursor[i] = run;                // becomes the scatter cursor
        run += d;
    }
    if (t == 1023) rowptr[n] = sums[1023];
}

__global__ void scatter_kernel(const int* __restrict__ src, const int* __restrict__ dst,
                               int* __restrict__ cursor, int* __restrict__ col, int E) {
    int e = blockIdx.x * blockDim.x + threadIdx.x;
    if (e < E) {
        int p = atomicAdd(&cursor[dst[e]], 1);
        col[p] = src[e];
    }
}

// ---------------- generic Y[n x 128] = act(LN?(X[n x K]) @ W + b) ----------------
// block = 256 threads, 16 rows per block. n must be divisible by 16 (it is).

template <int K, bool LN_IN, bool RELU>
__global__ __launch_bounds__(256) void gemm_kernel(const float* __restrict__ X,
                                                   const float* __restrict__ W,
                                                   const float* __restrict__ bias,
                                                   float* __restrict__ Y,
                                                   const float* __restrict__ g,
                                                   const float* __restrict__ bln) {
    static_assert(!LN_IN || K == 128, "LN input requires K==128");
    __shared__ __align__(16) float As[16 * K];
    const int t = threadIdx.x;
    const size_t row0 = (size_t)blockIdx.x * 16;

    for (int idx = t; idx < 16 * K; idx += 256) As[idx] = X[row0 * K + idx];
    __syncthreads();

    if (LN_IN) {
        const int w = t >> 6, l = t & 63;
        for (int q = 0; q < 4; ++q) {
            const int r = w * 4 + q;
            float a0 = As[r * K + l], a1 = As[r * K + 64 + l];
            float m = wave_sum(a0 + a1) * (1.0f / 128.0f);
            float d0 = a0 - m, d1 = a1 - m;
            float var = wave_sum(d0 * d0 + d1 * d1) * (1.0f / 128.0f);
            float rs = rsqrtf(var + EPS);
            As[r * K + l] = d0 * rs * g[l] + bln[l];
            As[r * K + 64 + l] = d1 * rs * g[64 + l] + bln[64 + l];
        }
        __syncthreads();
    }

    const int c0 = (t & 31) * 4;   // 32 col-groups of 4
    const int r0 = (t >> 5) * 2;   // 8 row-groups of 2
    v4f b4 = *(const v4f*)&bias[c0];
    v4f acc0 = b4, acc1 = b4;
#pragma unroll 4
    for (int k = 0; k < K; k += 4) {
        v4f a0 = *(const v4f*)&As[r0 * K + k];
        v4f a1 = *(const v4f*)&As[(r0 + 1) * K + k];
        v4f w0 = *(const v4f*)&W[(size_t)(k + 0) * HD + c0];
        v4f w1 = *(const v4f*)&W[(size_t)(k + 1) * HD + c0];
        v4f w2 = *(const v4f*)&W[(size_t)(k + 2) * HD + c0];
        v4f w3 = *(const v4f*)&W[(size_t)(k + 3) * HD + c0];
        acc0 += a0.x * w0 + a0.y * w1 + a0.z * w2 + a0.w * w3;
        acc1 += a1.x * w0 + a1.y * w1 + a1.z * w2 + a1.w * w3;
    }
    if (RELU) {
#pragma unroll
        for (int i = 0; i < 4; ++i) {
            acc0[i] = fmaxf(acc0[i], 0.0f);
            acc1[i] = fmaxf(acc1[i], 0.0f);
        }
    }
    *(v4f*)&Y[(row0 + r0) * HD + c0] = acc0;
    *(v4f*)&Y[(row0 + r0 + 1) * HD + c0] = acc1;
}

// ---------------- fused SAGE update ----------------
// out = relu(LN(mean1@Wl1 + bl1 [+ mean2@Wl2 + bl2] + xdst@(Wr1[+Wr2]))) + xdst
// block = 256 threads, 16 rows. In-place (out==xdst) is safe: xdst reads are row-local.

template <int HAS2>
__global__ __launch_bounds__(256) void update_kernel(
    const float* __restrict__ xdst, float* __restrict__ out,
    const float* __restrict__ src1, const int* __restrict__ rp1,
    const int* __restrict__ col1, const float* __restrict__ inv1,
    const float* __restrict__ Wl1, const float* __restrict__ bl1,
    const float* __restrict__ Wr1,
    const float* __restrict__ src2, const int* __restrict__ rp2,
    const int* __restrict__ col2, const float* __restrict__ inv2,
    const float* __restrict__ Wl2, const float* __restrict__ bl2,
    const float* __restrict__ Wr2,
    const float* __restrict__ g, const float* __restrict__ bln) {
    __shared__ __align__(16) float sA1[16 * 128];   // mean-agg #1, reused as h
    __shared__ __align__(16) float sXd[16 * 128];   // x_dst tile
    __shared__ __align__(16) float sA2[HAS2 ? 16 * 128 : 4];
    const int t = threadIdx.x;
    const int row0 = blockIdx.x * 16;
    const int w = t >> 6, l = t & 63;

    for (int idx = t; idx < 16 * 128; idx += 256)
        sXd[idx] = xdst[(size_t)row0 * 128 + idx];

    // Phase A: wave-per-row mean aggregation (gather via CSR)
    for (int q = 0; q < 4; ++q) {
        const int r = w * 4 + q;
        const int gr = row0 + r;
        {
            float a0 = 0.f, a1 = 0.f;
            const int e1 = rp1[gr + 1];
            for (int e = rp1[gr]; e < e1; ++e) {
                const float* p = src1 + (size_t)col1[e] * 128;
                a0 += p[l];
                a1 += p[64 + l];
            }
            const float iv = inv1[gr];
            sA1[r * 128 + l] = a0 * iv;
            sA1[r * 128 + 64 + l] = a1 * iv;
        }
        if constexpr (HAS2) {
            float a0 = 0.f, a1 = 0.f;
            const int e1 = rp2[gr + 1];
            for (int e = rp2[gr]; e < e1; ++e) {
                const float* p = src2 + (size_t)col2[e] * 128;
                a0 += p[l];
                a1 += p[64 + l];
            }
            const float iv = inv2[gr];
            sA2[r * 128 + l] = a0 * iv;
            sA2[r * 128 + 64 + l] = a1 * iv;
        }
    }
    __syncthreads();

    // Phase B: register-tiled GEMM, 2 rows x 4 cols per thread
    const int c0 = (t & 31) * 4;
    const int r0 = (t >> 5) * 2;
    v4f bias = *(const v4f*)&bl1[c0];
    if constexpr (HAS2) bias += *(const v4f*)&bl2[c0];
    v4f acc0 = bias, acc1 = bias;
#pragma unroll 2
    for (int k = 0; k < 128; k += 4) {
        {
            v4f a0 = *(const v4f*)&sA1[r0 * 128 + k];
            v4f a1 = *(const v4f*)&sA1[(r0 + 1) * 128 + k];
            v4f w0 = *(const v4f*)&Wl1[(k + 0) * 128 + c0];
            v4f w1 = *(const v4f*)&Wl1[(k + 1) * 128 + c0];
            v4f w2 = *(const v4f*)&Wl1[(k + 2) * 128 + c0];
            v4f w3 = *(const v4f*)&Wl1[(k + 3) * 128 + c0];
            acc0 += a0.x * w0 + a0.y * w1 + a0.z * w2 + a0.w * w3;
            acc1 += a1.x * w0 + a1.y * w1 + a1.z * w2 + a1.w * w3;
        }
        if constexpr (HAS2) {
            v4f a0 = *(const v4f*)&sA2[r0 * 128 + k];
            v4f a1 = *(const v4f*)&sA2[(r0 + 1) * 128 + k];
            v4f w0 = *(const v4f*)&Wl2[(k + 0) * 128 + c0];
            v4f w1 = *(const v4f*)&Wl2[(k + 1) * 128 + c0];
            v4f w2 = *(const v4f*)&Wl2[(k + 2) * 128 + c0];
            v4f w3 = *(const v4f*)&Wl2[(k + 3) * 128 + c0];
            acc0 += a0.x * w0 + a0.y * w1 + a0.z * w2 + a0.w * w3;
            acc1 += a1.x * w0 + a1.y * w1 + a1.z * w2 + a1.w * w3;
        }
        {
            v4f x0 = *(const v4f*)&sXd[r0 * 128 + k];
            v4f x1 = *(const v4f*)&sXd[(r0 + 1) * 128 + k];
            v4f u0 = *(const v4f*)&Wr1[(k + 0) * 128 + c0];
            v4f u1 = *(const v4f*)&Wr1[(k + 1) * 128 + c0];
            v4f u2 = *(const v4f*)&Wr1[(k + 2) * 128 + c0];
            v4f u3 = *(const v4f*)&Wr1[(k + 3) * 128 + c0];
            if constexpr (HAS2) {
                u0 += *(const v4f*)&Wr2[(k + 0) * 128 + c0];
                u1 += *(const v4f*)&Wr2[(k + 1) * 128 + c0];
                u2 += *(const v4f*)&Wr2[(k + 2) * 128 + c0];
                u3 += *(const v4f*)&Wr2[(k + 3) * 128 + c0];
            }
            acc0 += x0.x * u0 + x0.y * u1 + x0.z * u2 + x0.w * u3;
            acc1 += x1.x * u0 + x1.y * u1 + x1.z * u2 + x1.w * u3;
        }
    }
    __syncthreads();
    *(v4f*)&sA1[r0 * 128 + c0] = acc0;        // h overwrites agg1
    *(v4f*)&sA1[(r0 + 1) * 128 + c0] = acc1;
    __syncthreads();

    // Phase C: LayerNorm + ReLU + residual
    for (int q = 0; q < 4; ++q) {
        const int r = w * 4 + q;
        const size_t gr = (size_t)(row0 + r);
        float h0 = sA1[r * 128 + l], h1 = sA1[r * 128 + 64 + l];
        float m = wave_sum(h0 + h1) * (1.0f / 128.0f);
        float d0 = h0 - m, d1 = h1 - m;
        float var = wave_sum(d0 * d0 + d1 * d1) * (1.0f / 128.0f);
        float rs = rsqrtf(var + EPS);
        float y0 = d0 * rs * g[l] + bln[l];
        float y1 = d1 * rs * g[64 + l] + bln[64 + l];
        out[gr * 128 + l] = fmaxf(y0, 0.f) + sXd[r * 128 + l];
        out[gr * 128 + 64 + l] = fmaxf(y1, 0.f) + sXd[r * 128 + 64 + l];
    }
}

// ---------------- attention-gate weight folding: Wvo = Wv@Wo, bvo = bv@Wo + bo ----------------

__global__ __launch_bounds__(128) void fold_kernel(const float* __restrict__ Wv,
                                                   const float* __restrict__ bv,
                                                   const float* __restrict__ Wo,
                                                   const float* __restrict__ bo,
                                                   float* __restrict__ Wvo,
                                                   float* __restrict__ bvo) {
    const int c = threadIdx.x;
    const int r = blockIdx.x;
    if (r < 128) {
        float s = 0.f;
        for (int k = 0; k < 128; ++k) s += Wv[r * 128 + k] * Wo[k * 128 + c];
        Wvo[r * 128 + c] = s;
    } else {
        float s = bo[c];
        for (int k = 0; k < 128; ++k) s += bv[k] * Wo[k * 128 + c];
        bvo[c] = s;
    }
}

// ---------------- out[r] = dot(z[r], w2) + b2 ----------------

__global__ __launch_bounds__(256) void dot_kernel(const float* __restrict__ Z,
                                                  const float* __restrict__ w2,
                                                  const float* __restrict__ b2,
                                                  float* __restrict__ out, int n) {
    const int w = threadIdx.x >> 6, l = threadIdx.x & 63;
    const size_t row = (size_t)blockIdx.x * 4 + w;
    if (row < (size_t)n) {
        float v = Z[row * 128 + l] * w2[l] + Z[row * 128 + 64 + l] * w2[64 + l];
        v = wave_sum(v);
        if (l == 0) out[row] = v + b2[0];
    }
}

}  // namespace

extern "C" void kernel_launch(void* const* d_in, const int* in_sizes, int n_in,
                              void* d_out, int out_size, void* d_ws, size_t ws_size,
                              hipStream_t stream) {
    const float* x_user     = (const float*)d_in[0];
    const float* x_travel   = (const float*)d_in[1];
    float*       xv         = (float*)d_in[2];   // updated in place (harness restores inputs)
    const float* W_in_user  = (const float*)d_in[3];
    const float* b_in_user  = (const float*)d_in[4];
    const float* W_in_travel= (const float*)d_in[5];
    const float* b_in_travel= (const float*)d_in[6];
    const float* Wl         = (const float*)d_in[7];
    const float* bl         = (const float*)d_in[8];
    const float* Wr         = (const float*)d_in[9];
    const float* ln_g       = (const float*)d_in[10];
    const float* ln_b       = (const float*)d_in[11];
    // inputs 12..24: expert MLPs (dead) + attn_query/Wq/bq/Wk/bk (dead: softmax over 1 key == 1)
    const float* Wv_        = (const float*)d_in[25];
    const float* bv_        = (const float*)d_in[26];
    const float* Wo_        = (const float*)d_in[27];
    const float* bo_        = (const float*)d_in[28];
    const float* f_ln_g     = (const float*)d_in[29];
    const float* f_ln_b     = (const float*)d_in[30];
    const float* f_W1       = (const float*)d_in[31];
    const float* f_b1       = (const float*)d_in[32];
    const float* f_W2       = (const float*)d_in[33];
    const float* f_b2       = (const float*)d_in[34];
    const int*   ei_ut      = (const int*)d_in[35];
    const int*   ei_tu      = (const int*)d_in[36];
    const int*   ei_tv      = (const int*)d_in[37];
    const int*   ei_vt      = (const int*)d_in[38];
    const int E = in_sizes[35] / 2;

    // ---- workspace layout (~72 MB) ----
    char* wsb = (char*)d_ws;
    size_t off = 0;
    auto alloc = [&](size_t bytes) -> void* {
        off = (off + 511) & ~(size_t)511;
        void* p = wsb + off;
        off += bytes;
        return p;
    };
    float* xu   = (float*)alloc((size_t)NU * HD * 4);
    float* xt_a = (float*)alloc((size_t)NT * HD * 4);  // xt_a + xt_b contiguous: reused as
    float* xt_b = (float*)alloc((size_t)NT * HD * 4);  // the NV x 128 attn buffer at the end
    float* Wvo  = (float*)alloc(128 * 128 * 4);
    float* bvo  = (float*)alloc(128 * 4);

    int *rp[4], *cur[4], *colb[4];
    float* invb[4];
    const int ndst[4] = {NU, NT, NT, NV};  // tu, ut, vt, tv
    for (int i = 0; i < 4; ++i) {
        rp[i]   = (int*)alloc((size_t)(ndst[i] + 1) * 4);
        cur[i]  = (int*)alloc((size_t)ndst[i] * 4);
        colb[i] = (int*)alloc((size_t)E * 4);
        invb[i] = (float*)alloc((size_t)ndst[i] * 4);
    }

    auto build_csr = [&](const int* ei, int n_dst, int* rpp, int* curp, int* colp, float* invp) {
        const int* srcA = ei;
        const int* dstA = ei + E;
        hipMemsetAsync(curp, 0, (size_t)n_dst * 4, stream);
        hist_kernel<<<(E + 255) / 256, 256, 0, stream>>>(dstA, curp, E);
        scan_kernel<<<1, 1024, 0, stream>>>(curp, rpp, invp, n_dst);
        scatter_kernel<<<(E + 255) / 256, 256, 0, stream>>>(srcA, dstA, curp, colp, E);
    };
    build_csr(ei_tu, NU, rp[0], cur[0], colb[0], invb[0]);
    build_csr(ei_ut, NT, rp[1], cur[1], colb[1], invb[1]);
    build_csr(ei_vt, NT, rp[2], cur[2], colb[2], invb[2]);
    build_csr(ei_tv, NV, rp[3], cur[3], colb[3], invb[3]);

    // ---- input projections ----
    gemm_kernel<64, false, false><<<NU / 16, 256, 0, stream>>>(
        x_user, W_in_user, b_in_user, xu, nullptr, nullptr);
    gemm_kernel<32, false, false><<<NT / 16, 256, 0, stream>>>(
        x_travel, W_in_travel, b_in_travel, xt_a, nullptr, nullptr);

    // ---- 8 hetero-SAGE layers ----
    constexpr size_t WSZ = 128 * 128;
    float* xt_cur = xt_a;
    float* xt_nxt = xt_b;
    for (int i = 0; i < LAYERS; ++i) {
        const float* Wl_i = Wl + (size_t)i * 4 * WSZ;
        const float* Wr_i = Wr + (size_t)i * 4 * WSZ;
        const float* bl_i = bl + (size_t)i * 4 * 128;
        const float* g_i  = ln_g + (size_t)i * 3 * 128;
        const float* b_i  = ln_b + (size_t)i * 3 * 128;
        // travel: sage(xu via ut, weights[0]) + sage(xv via vt, weights[3]); must run
        // before xu/xv are overwritten
        update_kernel<1><<<NT / 16, 256, 0, stream>>>(
            xt_cur, xt_nxt,
            xu, rp[1], colb[1], invb[1], Wl_i + 0 * WSZ, bl_i + 0 * 128, Wr_i + 0 * WSZ,
            xv, rp[2], colb[2], invb[2], Wl_i + 3 * WSZ, bl_i + 3 * 128, Wr_i + 3 * WSZ,
            g_i + 1 * 128, b_i + 1 * 128);
        // user: sage(xt_cur via tu, weights[1]) — in place
        update_kernel<0><<<NU / 16, 256, 0, stream>>>(
            xu, xu,
            xt_cur, rp[0], colb[0], invb[0], Wl_i + 1 * WSZ, bl_i + 1 * 128, Wr_i + 1 * WSZ,
            nullptr, nullptr, nullptr, nullptr, nullptr, nullptr, nullptr,
            g_i + 0 * 128, b_i + 0 * 128);
        // visit: sage(xt_cur via tv, weights[2]) — in place
        update_kernel<0><<<NV / 16, 256, 0, stream>>>(
            xv, xv,
            xt_cur, rp[3], colb[3], invb[3], Wl_i + 2 * WSZ, bl_i + 2 * 128, Wr_i + 2 * WSZ,
            nullptr, nullptr, nullptr, nullptr, nullptr, nullptr, nullptr,
            g_i + 2 * 128, b_i + 2 * 128);
        float* tmp = xt_cur; xt_cur = xt_nxt; xt_nxt = tmp;
    }

    // ---- head: attn = xv @ (Wv@Wo) + (bv@Wo+bo); z = relu(LN(attn)@W1+b1); out = z@W2+b2 ----
    fold_kernel<<<129, 128, 0, stream>>>(Wv_, bv_, Wo_, bo_, Wvo, bvo);
    float* attn = xt_a;  // xt buffers (contiguous 51.2 MB) are dead now
    gemm_kernel<128, false, false><<<NV / 16, 256, 0, stream>>>(
        xv, Wvo, bvo, attn, nullptr, nullptr);
    gemm_kernel<128, true, true><<<NV / 16, 256, 0, stream>>>(
        attn, f_W1, f_b1, attn, f_ln_g, f_ln_b);
    dot_kernel<<<NV / 4, 256, 0, stream>>>(attn, f_W2, f_b2, (float*)d_out, NV);
}

// Round 2
// 6537.148 us; speedup vs baseline: 1.1678x; 1.1678x over previous
//
#include <hip/hip_runtime.h>

typedef float v4f __attribute__((ext_vector_type(4)));

namespace {

constexpr int NU = 20000;
constexpr int NT = 50000;
constexpr int NV = 100000;
constexpr int HD = 128;
constexpr int LAYERS = 8;
constexpr float EPS = 1e-5f;

__device__ __forceinline__ float wave_sum(float v) {
#pragma unroll
    for (int m = 32; m >= 1; m >>= 1) v += __shfl_xor(v, m, 64);
    return v;
}

// ---------------- CSR build (per edge type, grouped by destination) ----------------

__global__ void hist_kernel(const int* __restrict__ dst, int* __restrict__ deg, int E) {
    int e = blockIdx.x * blockDim.x + threadIdx.x;
    if (e < E) atomicAdd(&deg[dst[e]], 1);
}

__global__ __launch_bounds__(1024) void scan_kernel(int* __restrict__ deg_cursor,
                                                    int* __restrict__ rowptr,
                                                    float* __restrict__ inv, int n) {
    __shared__ int sums[1024];
    const int t = threadIdx.x;
    const int chunk = (n + 1023) / 1024;
    const int start = min(t * chunk, n);
    const int end = min(start + chunk, n);
    int s = 0;
    for (int i = start; i < end; ++i) s += deg_cursor[i];
    sums[t] = s;
    __syncthreads();
    for (int off = 1; off < 1024; off <<= 1) {
        int v = (t >= off) ? sums[t - off] : 0;
        __syncthreads();
        sums[t] += v;
        __syncthreads();
    }
    int run = (t == 0) ? 0 : sums[t - 1];
    for (int i = start; i < end; ++i) {
        int d = deg_cursor[i];
        rowptr[i] = run;
        inv[i] = 1.0f / (float)max(d, 1);   // mean = sum / max(cnt,1)
        deg_cursor[i] = run;                // becomes the scatter cursor
        run += d;
    }
    if (t == 1023) rowptr[n] = sums[1023];
}

__global__ void scatter_kernel(const int* __restrict__ src, const int* __restrict__ dst,
                               int* __restrict__ cursor, int* __restrict__ col, int E) {
    int e = blockIdx.x * blockDim.x + threadIdx.x;
    if (e < E) {
        int p = atomicAdd(&cursor[dst[e]], 1);
        col[p] = src[e];
    }
}

// ---------------- generic Y[n x 128] = act(LN?(X[n x K]) @ W + b) ----------------
// block = 256 threads, 16 rows per block. n must be divisible by 16 (it is).

template <int K, bool LN_IN, bool RELU>
__global__ __launch_bounds__(256) void gemm_kernel(const float* __restrict__ X,
                                                   const float* __restrict__ W,
                                                   const float* __restrict__ bias,
                                                   float* __restrict__ Y,
                                                   const float* __restrict__ g,
                                                   const float* __restrict__ bln) {
    static_assert(!LN_IN || K == 128, "LN input requires K==128");
    __shared__ __align__(16) float As[16 * K];
    const int t = threadIdx.x;
    const size_t row0 = (size_t)blockIdx.x * 16;

    for (int idx = t; idx < 16 * K; idx += 256) As[idx] = X[row0 * K + idx];
    __syncthreads();

    if (LN_IN) {
        const int w = t >> 6, l = t & 63;
        for (int q = 0; q < 4; ++q) {
            const int r = w * 4 + q;
            float a0 = As[r * K + l], a1 = As[r * K + 64 + l];
            float m = wave_sum(a0 + a1) * (1.0f / 128.0f);
            float d0 = a0 - m, d1 = a1 - m;
            float var = wave_sum(d0 * d0 + d1 * d1) * (1.0f / 128.0f);
            float rs = rsqrtf(var + EPS);
            As[r * K + l] = d0 * rs * g[l] + bln[l];
            As[r * K + 64 + l] = d1 * rs * g[64 + l] + bln[64 + l];
        }
        __syncthreads();
    }

    const int c0 = (t & 31) * 4;   // 32 col-groups of 4
    const int r0 = (t >> 5) * 2;   // 8 row-groups of 2
    v4f b4 = *(const v4f*)&bias[c0];
    v4f acc0 = b4, acc1 = b4;
#pragma unroll 4
    for (int k = 0; k < K; k += 4) {
        v4f a0 = *(const v4f*)&As[r0 * K + k];
        v4f a1 = *(const v4f*)&As[(r0 + 1) * K + k];
        v4f w0 = *(const v4f*)&W[(size_t)(k + 0) * HD + c0];
        v4f w1 = *(const v4f*)&W[(size_t)(k + 1) * HD + c0];
        v4f w2 = *(const v4f*)&W[(size_t)(k + 2) * HD + c0];
        v4f w3 = *(const v4f*)&W[(size_t)(k + 3) * HD + c0];
        acc0 += a0.x * w0 + a0.y * w1 + a0.z * w2 + a0.w * w3;
        acc1 += a1.x * w0 + a1.y * w1 + a1.z * w2 + a1.w * w3;
    }
    if (RELU) {
#pragma unroll
        for (int i = 0; i < 4; ++i) {
            acc0[i] = fmaxf(acc0[i], 0.0f);
            acc1[i] = fmaxf(acc1[i], 0.0f);
        }
    }
    *(v4f*)&Y[(row0 + r0) * HD + c0] = acc0;
    *(v4f*)&Y[(row0 + r0 + 1) * HD + c0] = acc1;
}

// ---------------- fused SAGE update ----------------
// out = relu(LN(mean1@Wl1 + bl1 [+ mean2@Wl2 + bl2] + xdst@(Wr1[+Wr2]))) + xdst
// block = 256 threads, 16 rows. In-place (out==xdst) is safe: xdst reads are row-local.
// Phase A gather: quarter-wave (16 lanes) per row, float4 per lane covering cols
// [cq, cq+4) and [cq+64, cq+68), 2 edges unrolled -> 4 global_load_dwordx4 in
// flight per iteration, 4 rows in parallel per wave, no cross-lane combine.

template <int HAS2>
__global__ __launch_bounds__(256) void update_kernel(
    const float* __restrict__ xdst, float* __restrict__ out,
    const float* __restrict__ src1, const int* __restrict__ rp1,
    const int* __restrict__ col1, const float* __restrict__ inv1,
    const float* __restrict__ Wl1, const float* __restrict__ bl1,
    const float* __restrict__ Wr1,
    const float* __restrict__ src2, const int* __restrict__ rp2,
    const int* __restrict__ col2, const float* __restrict__ inv2,
    const float* __restrict__ Wl2, const float* __restrict__ bl2,
    const float* __restrict__ Wr2,
    const float* __restrict__ g, const float* __restrict__ bln) {
    __shared__ __align__(16) float sA1[16 * 128];   // mean-agg #1, reused as h
    __shared__ __align__(16) float sXd[16 * 128];   // x_dst tile
    __shared__ __align__(16) float sA2[HAS2 ? 16 * 128 : 4];
    const int t = threadIdx.x;
    const int row0 = blockIdx.x * 16;
    const int w = t >> 6, l = t & 63;

    for (int idx = t; idx < 16 * 128; idx += 256)
        sXd[idx] = xdst[(size_t)row0 * 128 + idx];

    // Phase A: high-MLP mean aggregation (gather via CSR)
    const int rq = (w << 2) | (l >> 4);      // tile row 0..15 (quarter-wave per row)
    const int cq = (l & 15) * 4;             // column group; lane covers cq and cq+64
    const int grq = row0 + rq;
    {
        const int s0 = rp1[grq], e1 = rp1[grq + 1];
        v4f a0 = {0.f, 0.f, 0.f, 0.f}, a1 = a0, b0 = a0, b1 = a0;
        int e = s0;
        for (; e + 1 < e1; e += 2) {
            const float* p0 = src1 + (size_t)col1[e] * 128 + cq;
            const float* p1 = src1 + (size_t)col1[e + 1] * 128 + cq;
            a0 += *(const v4f*)p0;
            a1 += *(const v4f*)(p0 + 64);
            b0 += *(const v4f*)p1;
            b1 += *(const v4f*)(p1 + 64);
        }
        if (e < e1) {
            const float* p0 = src1 + (size_t)col1[e] * 128 + cq;
            a0 += *(const v4f*)p0;
            a1 += *(const v4f*)(p0 + 64);
        }
        const float iv = inv1[grq];
        *(v4f*)&sA1[rq * 128 + cq] = (a0 + b0) * iv;
        *(v4f*)&sA1[rq * 128 + 64 + cq] = (a1 + b1) * iv;
    }
    if constexpr (HAS2) {
        const int s0 = rp2[grq], e1 = rp2[grq + 1];
        v4f a0 = {0.f, 0.f, 0.f, 0.f}, a1 = a0, b0 = a0, b1 = a0;
        int e = s0;
        for (; e + 1 < e1; e += 2) {
            const float* p0 = src2 + (size_t)col2[e] * 128 + cq;
            const float* p1 = src2 + (size_t)col2[e + 1] * 128 + cq;
            a0 += *(const v4f*)p0;
            a1 += *(const v4f*)(p0 + 64);
            b0 += *(const v4f*)p1;
            b1 += *(const v4f*)(p1 + 64);
        }
        if (e < e1) {
            const float* p0 = src2 + (size_t)col2[e] * 128 + cq;
            a0 += *(const v4f*)p0;
            a1 += *(const v4f*)(p0 + 64);
        }
        const float iv = inv2[grq];
        *(v4f*)&sA2[rq * 128 + cq] = (a0 + b0) * iv;
        *(v4f*)&sA2[rq * 128 + 64 + cq] = (a1 + b1) * iv;
    }
    __syncthreads();

    // Phase B: register-tiled GEMM, 2 rows x 4 cols per thread
    const int c0 = (t & 31) * 4;
    const int r0 = (t >> 5) * 2;
    v4f bias = *(const v4f*)&bl1[c0];
    if constexpr (HAS2) bias += *(const v4f*)&bl2[c0];
    v4f acc0 = bias, acc1 = bias;
#pragma unroll 2
    for (int k = 0; k < 128; k += 4) {
        {
            v4f a0 = *(const v4f*)&sA1[r0 * 128 + k];
            v4f a1 = *(const v4f*)&sA1[(r0 + 1) * 128 + k];
            v4f w0 = *(const v4f*)&Wl1[(k + 0) * 128 + c0];
            v4f w1 = *(const v4f*)&Wl1[(k + 1) * 128 + c0];
            v4f w2 = *(const v4f*)&Wl1[(k + 2) * 128 + c0];
            v4f w3 = *(const v4f*)&Wl1[(k + 3) * 128 + c0];
            acc0 += a0.x * w0 + a0.y * w1 + a0.z * w2 + a0.w * w3;
            acc1 += a1.x * w0 + a1.y * w1 + a1.z * w2 + a1.w * w3;
        }
        if constexpr (HAS2) {
            v4f a0 = *(const v4f*)&sA2[r0 * 128 + k];
            v4f a1 = *(const v4f*)&sA2[(r0 + 1) * 128 + k];
            v4f w0 = *(const v4f*)&Wl2[(k + 0) * 128 + c0];
            v4f w1 = *(const v4f*)&Wl2[(k + 1) * 128 + c0];
            v4f w2 = *(const v4f*)&Wl2[(k + 2) * 128 + c0];
            v4f w3 = *(const v4f*)&Wl2[(k + 3) * 128 + c0];
            acc0 += a0.x * w0 + a0.y * w1 + a0.z * w2 + a0.w * w3;
            acc1 += a1.x * w0 + a1.y * w1 + a1.z * w2 + a1.w * w3;
        }
        {
            v4f x0 = *(const v4f*)&sXd[r0 * 128 + k];
            v4f x1 = *(const v4f*)&sXd[(r0 + 1) * 128 + k];
            v4f u0 = *(const v4f*)&Wr1[(k + 0) * 128 + c0];
            v4f u1 = *(const v4f*)&Wr1[(k + 1) * 128 + c0];
            v4f u2 = *(const v4f*)&Wr1[(k + 2) * 128 + c0];
            v4f u3 = *(const v4f*)&Wr1[(k + 3) * 128 + c0];
            if constexpr (HAS2) {
                u0 += *(const v4f*)&Wr2[(k + 0) * 128 + c0];
                u1 += *(const v4f*)&Wr2[(k + 1) * 128 + c0];
                u2 += *(const v4f*)&Wr2[(k + 2) * 128 + c0];
                u3 += *(const v4f*)&Wr2[(k + 3) * 128 + c0];
            }
            acc0 += x0.x * u0 + x0.y * u1 + x0.z * u2 + x0.w * u3;
            acc1 += x1.x * u0 + x1.y * u1 + x1.z * u2 + x1.w * u3;
        }
    }
    __syncthreads();
    *(v4f*)&sA1[r0 * 128 + c0] = acc0;        // h overwrites agg1
    *(v4f*)&sA1[(r0 + 1) * 128 + c0] = acc1;
    __syncthreads();

    // Phase C: LayerNorm + ReLU + residual
    for (int q = 0; q < 4; ++q) {
        const int r = w * 4 + q;
        const size_t gr = (size_t)(row0 + r);
        float h0 = sA1[r * 128 + l], h1 = sA1[r * 128 + 64 + l];
        float m = wave_sum(h0 + h1) * (1.0f / 128.0f);
        float d0 = h0 - m, d1 = h1 - m;
        float var = wave_sum(d0 * d0 + d1 * d1) * (1.0f / 128.0f);
        float rs = rsqrtf(var + EPS);
        float y0 = d0 * rs * g[l] + bln[l];
        float y1 = d1 * rs * g[64 + l] + bln[64 + l];
        out[gr * 128 + l] = fmaxf(y0, 0.f) + sXd[r * 128 + l];
        out[gr * 128 + 64 + l] = fmaxf(y1, 0.f) + sXd[r * 128 + 64 + l];
    }
}

// ---------------- attention-gate weight folding: Wvo = Wv@Wo, bvo = bv@Wo + bo ----------------

__global__ __launch_bounds__(128) void fold_kernel(const float* __restrict__ Wv,
                                                   const float* __restrict__ bv,
                                                   const float* __restrict__ Wo,
                                                   const float* __restrict__ bo,
                                                   float* __restrict__ Wvo,
                                                   float* __restrict__ bvo) {
    const int c = threadIdx.x;
    const int r = blockIdx.x;
    if (r < 128) {
        float s = 0.f;
        for (int k = 0; k < 128; ++k) s += Wv[r * 128 + k] * Wo[k * 128 + c];
        Wvo[r * 128 + c] = s;
    } else {
        float s = bo[c];
        for (int k = 0; k < 128; ++k) s += bv[k] * Wo[k * 128 + c];
        bvo[c] = s;
    }
}

// ---------------- out[r] = dot(z[r], w2) + b2 ----------------

__global__ __launch_bounds__(256) void dot_kernel(const float* __restrict__ Z,
                                                  const float* __restrict__ w2,
                                                  const float* __restrict__ b2,
                                                  float* __restrict__ out, int n) {
    const int w = threadIdx.x >> 6, l = threadIdx.x & 63;
    const size_t row = (size_t)blockIdx.x * 4 + w;
    if (row < (size_t)n) {
        float v = Z[row * 128 + l] * w2[l] + Z[row * 128 + 64 + l] * w2[64 + l];
        v = wave_sum(v);
        if (l == 0) out[row] = v + b2[0];
    }
}

}  // namespace

extern "C" void kernel_launch(void* const* d_in, const int* in_sizes, int n_in,
                              void* d_out, int out_size, void* d_ws, size_t ws_size,
                              hipStream_t stream) {
    const float* x_user     = (const float*)d_in[0];
    const float* x_travel   = (const float*)d_in[1];
    float*       xv         = (float*)d_in[2];   // updated in place (harness restores inputs)
    const float* W_in_user  = (const float*)d_in[3];
    const float* b_in_user  = (const float*)d_in[4];
    const float* W_in_travel= (const float*)d_in[5];
    const float* b_in_travel= (const float*)d_in[6];
    const float* Wl         = (const float*)d_in[7];
    const float* bl         = (const float*)d_in[8];
    const float* Wr         = (const float*)d_in[9];
    const float* ln_g       = (const float*)d_in[10];
    const float* ln_b       = (const float*)d_in[11];
    // inputs 12..24: expert MLPs (dead) + attn_query/Wq/bq/Wk/bk (dead: softmax over 1 key == 1)
    const float* Wv_        = (const float*)d_in[25];
    const float* bv_        = (const float*)d_in[26];
    const float* Wo_        = (const float*)d_in[27];
    const float* bo_        = (const float*)d_in[28];
    const float* f_ln_g     = (const float*)d_in[29];
    const float* f_ln_b     = (const float*)d_in[30];
    const float* f_W1       = (const float*)d_in[31];
    const float* f_b1       = (const float*)d_in[32];
    const float* f_W2       = (const float*)d_in[33];
    const float* f_b2       = (const float*)d_in[34];
    const int*   ei_ut      = (const int*)d_in[35];
    const int*   ei_tu      = (const int*)d_in[36];
    const int*   ei_tv      = (const int*)d_in[37];
    const int*   ei_vt      = (const int*)d_in[38];
    const int E = in_sizes[35] / 2;

    // ---- workspace layout (~72 MB) ----
    char* wsb = (char*)d_ws;
    size_t off = 0;
    auto alloc = [&](size_t bytes) -> void* {
        off = (off + 511) & ~(size_t)511;
        void* p = wsb + off;
        off += bytes;
        return p;
    };
    float* xu   = (float*)alloc((size_t)NU * HD * 4);
    float* xt_a = (float*)alloc((size_t)NT * HD * 4);  // xt_a + xt_b contiguous: reused as
    float* xt_b = (float*)alloc((size_t)NT * HD * 4);  // the NV x 128 attn buffer at the end
    float* Wvo  = (float*)alloc(128 * 128 * 4);
    float* bvo  = (float*)alloc(128 * 4);

    int *rp[4], *cur[4], *colb[4];
    float* invb[4];
    const int ndst[4] = {NU, NT, NT, NV};  // tu, ut, vt, tv
    for (int i = 0; i < 4; ++i) {
        rp[i]   = (int*)alloc((size_t)(ndst[i] + 1) * 4);
        cur[i]  = (int*)alloc((size_t)ndst[i] * 4);
        colb[i] = (int*)alloc((size_t)E * 4);
        invb[i] = (float*)alloc((size_t)ndst[i] * 4);
    }

    auto build_csr = [&](const int* ei, int n_dst, int* rpp, int* curp, int* colp, float* invp) {
        const int* srcA = ei;
        const int* dstA = ei + E;
        hipMemsetAsync(curp, 0, (size_t)n_dst * 4, stream);
        hist_kernel<<<(E + 255) / 256, 256, 0, stream>>>(dstA, curp, E);
        scan_kernel<<<1, 1024, 0, stream>>>(curp, rpp, invp, n_dst);
        scatter_kernel<<<(E + 255) / 256, 256, 0, stream>>>(srcA, dstA, curp, colp, E);
    };
    build_csr(ei_tu, NU, rp[0], cur[0], colb[0], invb[0]);
    build_csr(ei_ut, NT, rp[1], cur[1], colb[1], invb[1]);
    build_csr(ei_vt, NT, rp[2], cur[2], colb[2], invb[2]);
    build_csr(ei_tv, NV, rp[3], cur[3], colb[3], invb[3]);

    // ---- input projections ----
    gemm_kernel<64, false, false><<<NU / 16, 256, 0, stream>>>(
        x_user, W_in_user, b_in_user, xu, nullptr, nullptr);
    gemm_kernel<32, false, false><<<NT / 16, 256, 0, stream>>>(
        x_travel, W_in_travel, b_in_travel, xt_a, nullptr, nullptr);

    // ---- 8 hetero-SAGE layers ----
    constexpr size_t WSZ = 128 * 128;
    float* xt_cur = xt_a;
    float* xt_nxt = xt_b;
    for (int i = 0; i < LAYERS; ++i) {
        const float* Wl_i = Wl + (size_t)i * 4 * WSZ;
        const float* Wr_i = Wr + (size_t)i * 4 * WSZ;
        const float* bl_i = bl + (size_t)i * 4 * 128;
        const float* g_i  = ln_g + (size_t)i * 3 * 128;
        const float* b_i  = ln_b + (size_t)i * 3 * 128;
        // travel: sage(xu via ut, weights[0]) + sage(xv via vt, weights[3]); must run
        // before xu/xv are overwritten
        update_kernel<1><<<NT / 16, 256, 0, stream>>>(
            xt_cur, xt_nxt,
            xu, rp[1], colb[1], invb[1], Wl_i + 0 * WSZ, bl_i + 0 * 128, Wr_i + 0 * WSZ,
            xv, rp[2], colb[2], invb[2], Wl_i + 3 * WSZ, bl_i + 3 * 128, Wr_i + 3 * WSZ,
            g_i + 1 * 128, b_i + 1 * 128);
        // user: sage(xt_cur via tu, weights[1]) — in place
        update_kernel<0><<<NU / 16, 256, 0, stream>>>(
            xu, xu,
            xt_cur, rp[0], colb[0], invb[0], Wl_i + 1 * WSZ, bl_i + 1 * 128, Wr_i + 1 * WSZ,
            nullptr, nullptr, nullptr, nullptr, nullptr, nullptr, nullptr,
            g_i + 0 * 128, b_i + 0 * 128);
        // visit: sage(xt_cur via tv, weights[2]) — in place
        update_kernel<0><<<NV / 16, 256, 0, stream>>>(
            xv, xv,
            xt_cur, rp[3], colb[3], invb[3], Wl_i + 2 * WSZ, bl_i + 2 * 128, Wr_i + 2 * WSZ,
            nullptr, nullptr, nullptr, nullptr, nullptr, nullptr, nullptr,
            g_i + 2 * 128, b_i + 2 * 128);
        float* tmp = xt_cur; xt_cur = xt_nxt; xt_nxt = tmp;
    }

    // ---- head: attn = xv @ (Wv@Wo) + (bv@Wo+bo); z = relu(LN(attn)@W1+b1); out = z@W2+b2 ----
    fold_kernel<<<129, 128, 0, stream>>>(Wv_, bv_, Wo_, bo_, Wvo, bvo);
    float* attn = xt_a;  // xt buffers (contiguous 51.2 MB) are dead now
    gemm_kernel<128, false, false><<<NV / 16, 256, 0, stream>>>(
        xv, Wvo, bvo, attn, nullptr, nullptr);
    gemm_kernel<128, true, true><<<NV / 16, 256, 0, stream>>>(
        attn, f_W1, f_b1, attn, f_ln_g, f_ln_b);
    dot_kernel<<<NV / 4, 256, 0, stream>>>(attn, f_W2, f_b2, (float*)d_out, NV);
}

// Round 3
// 5070.636 us; speedup vs baseline: 1.5055x; 1.2892x over previous
//
#include <hip/hip_runtime.h>

typedef float v4f __attribute__((ext_vector_type(4)));

namespace {

constexpr int NU = 20000;
constexpr int NT = 50000;
constexpr int NV = 100000;
constexpr int HD = 128;
constexpr int LAYERS = 8;
constexpr float EPS = 1e-5f;
constexpr int CAP = 640;   // staged col indices per CSR per block (16 rows)

__device__ __forceinline__ float wave_sum(float v) {
#pragma unroll
    for (int m = 32; m >= 1; m >>= 1) v += __shfl_xor(v, m, 64);
    return v;
}

// ---------------- CSR build (per edge type, grouped by destination) ----------------

__global__ void hist_kernel(const int* __restrict__ dst, int* __restrict__ deg, int E) {
    int e = blockIdx.x * blockDim.x + threadIdx.x;
    if (e < E) atomicAdd(&deg[dst[e]], 1);
}

__global__ __launch_bounds__(1024) void scan_kernel(int* __restrict__ deg_cursor,
                                                    int* __restrict__ rowptr,
                                                    float* __restrict__ inv, int n) {
    __shared__ int sums[1024];
    const int t = threadIdx.x;
    const int chunk = (n + 1023) / 1024;
    const int start = min(t * chunk, n);
    const int end = min(start + chunk, n);
    int s = 0;
    for (int i = start; i < end; ++i) s += deg_cursor[i];
    sums[t] = s;
    __syncthreads();
    for (int off = 1; off < 1024; off <<= 1) {
        int v = (t >= off) ? sums[t - off] : 0;
        __syncthreads();
        sums[t] += v;
        __syncthreads();
    }
    int run = (t == 0) ? 0 : sums[t - 1];
    for (int i = start; i < end; ++i) {
        int d = deg_cursor[i];
        rowptr[i] = run;
        inv[i] = 1.0f / (float)max(d, 1);
        deg_cursor[i] = run;
        run += d;
    }
    if (t == 1023) rowptr[n] = sums[1023];
}

__global__ void scatter_kernel(const int* __restrict__ src, const int* __restrict__ dst,
                               int* __restrict__ cursor, int* __restrict__ col, int E) {
    int e = blockIdx.x * blockDim.x + threadIdx.x;
    if (e < E) {
        int p = atomicAdd(&cursor[dst[e]], 1);
        col[p] = src[e];
    }
}

// ---------------- Wr fold for travel: WrT[l] = Wr[l,0] + Wr[l,3] ----------------

__global__ __launch_bounds__(256) void addw_kernel(const float* __restrict__ Wr,
                                                   float* __restrict__ WrT) {
    int idx = blockIdx.x * 256 + threadIdx.x;       // 8 * 16384
    int layer = idx >> 14, k = idx & 16383;
    WrT[idx] = Wr[(size_t)layer * 4 * 16384 + k] + Wr[(size_t)layer * 4 * 16384 + 3 * 16384 + k];
}

// ---------------- per-row gather: mean over CSR neighbors ----------------
// Quarter-wave (16 lanes) per row; lane covers cols [cq,cq+4) and [cq+64,cq+68).
// Col indices come from LDS (staged) -> no col->feature load chain; 4-edge unroll
// -> 8 global_load_dwordx4 in flight per lane.

__device__ __forceinline__ void gather_row(
    const float* __restrict__ src, const int* __restrict__ colg,
    const int* __restrict__ sCol, int off_r, int s0, int e1,
    int cq, float iv, float* __restrict__ outRow) {
    const int d = e1 - s0;
    const int jst = min(d, max(0, CAP - off_r));
    v4f a0 = {0.f, 0.f, 0.f, 0.f}, a1 = a0, b0 = a0, b1 = a0;
    v4f c0 = a0, c1 = a0, d0 = a0, d1 = a0;
    int j = 0;
    for (; j + 4 <= jst; j += 4) {
        const int i0 = sCol[off_r + j + 0];
        const int i1 = sCol[off_r + j + 1];
        const int i2 = sCol[off_r + j + 2];
        const int i3 = sCol[off_r + j + 3];
        const float* p0 = src + (size_t)i0 * 128 + cq;
        const float* p1 = src + (size_t)i1 * 128 + cq;
        const float* p2 = src + (size_t)i2 * 128 + cq;
        const float* p3 = src + (size_t)i3 * 128 + cq;
        v4f t0 = *(const v4f*)p0, u0 = *(const v4f*)(p0 + 64);
        v4f t1 = *(const v4f*)p1, u1 = *(const v4f*)(p1 + 64);
        v4f t2 = *(const v4f*)p2, u2 = *(const v4f*)(p2 + 64);
        v4f t3 = *(const v4f*)p3, u3 = *(const v4f*)(p3 + 64);
        a0 += t0; a1 += u0; b0 += t1; b1 += u1;
        c0 += t2; c1 += u2; d0 += t3; d1 += u3;
    }
    for (; j < jst; ++j) {
        const int i0 = sCol[off_r + j];
        const float* p0 = src + (size_t)i0 * 128 + cq;
        a0 += *(const v4f*)p0;
        a1 += *(const v4f*)(p0 + 64);
    }
    for (int e = s0 + jst; e < e1; ++e) {   // overflow fallback (rare)
        const int i0 = colg[e];
        const float* p0 = src + (size_t)i0 * 128 + cq;
        a0 += *(const v4f*)p0;
        a1 += *(const v4f*)(p0 + 64);
    }
    v4f r0 = (a0 + b0) + (c0 + d0);
    v4f r1 = (a1 + b1) + (c1 + d1);
    *(v4f*)&outRow[cq] = r0 * iv;
    *(v4f*)&outRow[64 + cq] = r1 * iv;
}

// ---------------- fused SAGE update body ----------------
// out = relu(LN(mean1@Wl1 + bl1 [+ mean2@Wl2 + bl2] + xdst@WrU)) + xdst
// WrU is pre-folded (Wr1+Wr2) for the travel case. In-place safe (row-local).

template <int HAS2>
__device__ __forceinline__ void sage_body(
    int row0, const float* __restrict__ xdst, float* __restrict__ out,
    const float* __restrict__ src1, const int* __restrict__ rp1,
    const int* __restrict__ col1, const float* __restrict__ inv1,
    const float* __restrict__ Wl1, const float* __restrict__ bl1,
    const float* __restrict__ src2, const int* __restrict__ rp2,
    const int* __restrict__ col2, const float* __restrict__ inv2,
    const float* __restrict__ Wl2, const float* __restrict__ bl2,
    const float* __restrict__ WrU,
    const float* __restrict__ g, const float* __restrict__ bln,
    float* sA1, float* sXd, float* sA2, int* sC1, int* sC2) {
    const int t = threadIdx.x;
    const int w = t >> 6, l = t & 63;

    for (int idx = t; idx < 2048; idx += 256)
        sXd[idx] = xdst[(size_t)row0 * 128 + idx];

    const int eb1 = rp1[row0];
    const int cnt1 = min(rp1[row0 + 16] - eb1, CAP);
    for (int i = t; i < cnt1; i += 256) sC1[i] = col1[eb1 + i];
    int eb2 = 0;
    if constexpr (HAS2) {
        eb2 = rp2[row0];
        const int cnt2 = min(rp2[row0 + 16] - eb2, CAP);
        for (int i = t; i < cnt2; i += 256) sC2[i] = col2[eb2 + i];
    }
    __syncthreads();

    // Phase A: gather
    const int rq = (w << 2) | (l >> 4);
    const int cq = (l & 15) * 4;
    const int grq = row0 + rq;
    {
        const int s0 = rp1[grq], e1 = rp1[grq + 1];
        gather_row(src1, col1, sC1, s0 - eb1, s0, e1, cq, inv1[grq], &sA1[rq * 128]);
    }
    if constexpr (HAS2) {
        const int s0 = rp2[grq], e1 = rp2[grq + 1];
        gather_row(src2, col2, sC2, s0 - eb2, s0, e1, cq, inv2[grq], &sA2[rq * 128]);
    }
    __syncthreads();

    // Phase B: register-tiled GEMM, 2 rows x 4 cols per thread
    const int c0 = (t & 31) * 4;
    const int r0 = (t >> 5) * 2;
    v4f bias = *(const v4f*)&bl1[c0];
    if constexpr (HAS2) bias += *(const v4f*)&bl2[c0];
    v4f acc0 = bias, acc1 = bias;
#pragma unroll 2
    for (int k = 0; k < 128; k += 4) {
        {
            v4f a0 = *(const v4f*)&sA1[r0 * 128 + k];
            v4f a1 = *(const v4f*)&sA1[(r0 + 1) * 128 + k];
            v4f w0 = *(const v4f*)&Wl1[(k + 0) * 128 + c0];
            v4f w1 = *(const v4f*)&Wl1[(k + 1) * 128 + c0];
            v4f w2 = *(const v4f*)&Wl1[(k + 2) * 128 + c0];
            v4f w3 = *(const v4f*)&Wl1[(k + 3) * 128 + c0];
            acc0 += a0.x * w0 + a0.y * w1 + a0.z * w2 + a0.w * w3;
            acc1 += a1.x * w0 + a1.y * w1 + a1.z * w2 + a1.w * w3;
        }
        if constexpr (HAS2) {
            v4f a0 = *(const v4f*)&sA2[r0 * 128 + k];
            v4f a1 = *(const v4f*)&sA2[(r0 + 1) * 128 + k];
            v4f w0 = *(const v4f*)&Wl2[(k + 0) * 128 + c0];
            v4f w1 = *(const v4f*)&Wl2[(k + 1) * 128 + c0];
            v4f w2 = *(const v4f*)&Wl2[(k + 2) * 128 + c0];
            v4f w3 = *(const v4f*)&Wl2[(k + 3) * 128 + c0];
            acc0 += a0.x * w0 + a0.y * w1 + a0.z * w2 + a0.w * w3;
            acc1 += a1.x * w0 + a1.y * w1 + a1.z * w2 + a1.w * w3;
        }
        {
            v4f x0 = *(const v4f*)&sXd[r0 * 128 + k];
            v4f x1 = *(const v4f*)&sXd[(r0 + 1) * 128 + k];
            v4f u0 = *(const v4f*)&WrU[(k + 0) * 128 + c0];
            v4f u1 = *(const v4f*)&WrU[(k + 1) * 128 + c0];
            v4f u2 = *(const v4f*)&WrU[(k + 2) * 128 + c0];
            v4f u3 = *(const v4f*)&WrU[(k + 3) * 128 + c0];
            acc0 += x0.x * u0 + x0.y * u1 + x0.z * u2 + x0.w * u3;
            acc1 += x1.x * u0 + x1.y * u1 + x1.z * u2 + x1.w * u3;
        }
    }
    __syncthreads();
    *(v4f*)&sA1[r0 * 128 + c0] = acc0;        // h overwrites agg1
    *(v4f*)&sA1[(r0 + 1) * 128 + c0] = acc1;
    __syncthreads();

    // Phase C: LayerNorm + ReLU + residual
    for (int q = 0; q < 4; ++q) {
        const int r = w * 4 + q;
        const size_t gr = (size_t)(row0 + r);
        float h0 = sA1[r * 128 + l], h1 = sA1[r * 128 + 64 + l];
        float m = wave_sum(h0 + h1) * (1.0f / 128.0f);
        float d0 = h0 - m, d1 = h1 - m;
        float var = wave_sum(d0 * d0 + d1 * d1) * (1.0f / 128.0f);
        float rs = rsqrtf(var + EPS);
        float y0 = d0 * rs * g[l] + bln[l];
        float y1 = d1 * rs * g[64 + l] + bln[64 + l];
        out[gr * 128 + l] = fmaxf(y0, 0.f) + sXd[r * 128 + l];
        out[gr * 128 + 64 + l] = fmaxf(y1, 0.f) + sXd[r * 128 + 64 + l];
    }
}

struct UpdParams {
    const float* xdst; float* out;
    const float* src1; const int* rp1; const int* col1; const float* inv1;
    const float* Wl1; const float* bl1; const float* Wr1;
    const float* g; const float* bln;
};

__global__ __launch_bounds__(256, 4) void travel_kernel(
    const float* xdst, float* out,
    const float* src1, const int* rp1, const int* col1, const float* inv1,
    const float* Wl1, const float* bl1,
    const float* src2, const int* rp2, const int* col2, const float* inv2,
    const float* Wl2, const float* bl2,
    const float* WrT, const float* g, const float* bln) {
    __shared__ __align__(16) float sA1[2048];
    __shared__ __align__(16) float sXd[2048];
    __shared__ __align__(16) float sA2[2048];
    __shared__ int sC1[CAP];
    __shared__ int sC2[CAP];
    sage_body<1>(blockIdx.x * 16, xdst, out,
                 src1, rp1, col1, inv1, Wl1, bl1,
                 src2, rp2, col2, inv2, Wl2, bl2,
                 WrT, g, bln, sA1, sXd, sA2, sC1, sC2);
}

__global__ __launch_bounds__(256, 4) void uv_kernel(UpdParams U, UpdParams V, int nbU) {
    __shared__ __align__(16) float sA1[2048];
    __shared__ __align__(16) float sXd[2048];
    __shared__ int sC1[CAP];
    const bool isU = (int)blockIdx.x < nbU;
    const UpdParams& P = isU ? U : V;
    const int row0 = (isU ? blockIdx.x : blockIdx.x - nbU) * 16;
    sage_body<0>(row0, P.xdst, P.out,
                 P.src1, P.rp1, P.col1, P.inv1, P.Wl1, P.bl1,
                 nullptr, nullptr, nullptr, nullptr, nullptr, nullptr,
                 P.Wr1, P.g, P.bln, sA1, sXd, nullptr, sC1, nullptr);
}

// ---------------- generic Y[n x 128] = act(LN?(X[n x K]) @ W + b) ----------------

template <int K, bool LN_IN, bool RELU>
__global__ __launch_bounds__(256) void gemm_kernel(const float* __restrict__ X,
                                                   const float* __restrict__ W,
                                                   const float* __restrict__ bias,
                                                   float* __restrict__ Y,
                                                   const float* __restrict__ g,
                                                   const float* __restrict__ bln) {
    static_assert(!LN_IN || K == 128, "LN input requires K==128");
    __shared__ __align__(16) float As[16 * K];
    const int t = threadIdx.x;
    const size_t row0 = (size_t)blockIdx.x * 16;

    for (int idx = t; idx < 16 * K; idx += 256) As[idx] = X[row0 * K + idx];
    __syncthreads();

    if (LN_IN) {
        const int w = t >> 6, l = t & 63;
        for (int q = 0; q < 4; ++q) {
            const int r = w * 4 + q;
            float a0 = As[r * K + l], a1 = As[r * K + 64 + l];
            float m = wave_sum(a0 + a1) * (1.0f / 128.0f);
            float d0 = a0 - m, d1 = a1 - m;
            float var = wave_sum(d0 * d0 + d1 * d1) * (1.0f / 128.0f);
            float rs = rsqrtf(var + EPS);
            As[r * K + l] = d0 * rs * g[l] + bln[l];
            As[r * K + 64 + l] = d1 * rs * g[64 + l] + bln[64 + l];
        }
        __syncthreads();
    }

    const int c0 = (t & 31) * 4;
    const int r0 = (t >> 5) * 2;
    v4f b4 = *(const v4f*)&bias[c0];
    v4f acc0 = b4, acc1 = b4;
#pragma unroll 4
    for (int k = 0; k < K; k += 4) {
        v4f a0 = *(const v4f*)&As[r0 * K + k];
        v4f a1 = *(const v4f*)&As[(r0 + 1) * K + k];
        v4f w0 = *(const v4f*)&W[(size_t)(k + 0) * HD + c0];
        v4f w1 = *(const v4f*)&W[(size_t)(k + 1) * HD + c0];
        v4f w2 = *(const v4f*)&W[(size_t)(k + 2) * HD + c0];
        v4f w3 = *(const v4f*)&W[(size_t)(k + 3) * HD + c0];
        acc0 += a0.x * w0 + a0.y * w1 + a0.z * w2 + a0.w * w3;
        acc1 += a1.x * w0 + a1.y * w1 + a1.z * w2 + a1.w * w3;
    }
    if (RELU) {
#pragma unroll
        for (int i = 0; i < 4; ++i) {
            acc0[i] = fmaxf(acc0[i], 0.0f);
            acc1[i] = fmaxf(acc1[i], 0.0f);
        }
    }
    *(v4f*)&Y[(row0 + r0) * HD + c0] = acc0;
    *(v4f*)&Y[(row0 + r0 + 1) * HD + c0] = acc1;
}

// ---------------- attention-gate weight folding: Wvo = Wv@Wo, bvo = bv@Wo + bo ----------------

__global__ __launch_bounds__(128) void fold_kernel(const float* __restrict__ Wv,
                                                   const float* __restrict__ bv,
                                                   const float* __restrict__ Wo,
                                                   const float* __restrict__ bo,
                                                   float* __restrict__ Wvo,
                                                   float* __restrict__ bvo) {
    const int c = threadIdx.x;
    const int r = blockIdx.x;
    if (r < 128) {
        float s = 0.f;
        for (int k = 0; k < 128; ++k) s += Wv[r * 128 + k] * Wo[k * 128 + c];
        Wvo[r * 128 + c] = s;
    } else {
        float s = bo[c];
        for (int k = 0; k < 128; ++k) s += bv[k] * Wo[k * 128 + c];
        bvo[c] = s;
    }
}

// ---------------- out[r] = dot(z[r], w2) + b2 ----------------

__global__ __launch_bounds__(256) void dot_kernel(const float* __restrict__ Z,
                                                  const float* __restrict__ w2,
                                                  const float* __restrict__ b2,
                                                  float* __restrict__ out, int n) {
    const int w = threadIdx.x >> 6, l = threadIdx.x & 63;
    const size_t row = (size_t)blockIdx.x * 4 + w;
    if (row < (size_t)n) {
        float v = Z[row * 128 + l] * w2[l] + Z[row * 128 + 64 + l] * w2[64 + l];
        v = wave_sum(v);
        if (l == 0) out[row] = v + b2[0];
    }
}

}  // namespace

extern "C" void kernel_launch(void* const* d_in, const int* in_sizes, int n_in,
                              void* d_out, int out_size, void* d_ws, size_t ws_size,
                              hipStream_t stream) {
    const float* x_user     = (const float*)d_in[0];
    const float* x_travel   = (const float*)d_in[1];
    float*       xv         = (float*)d_in[2];   // updated in place (harness restores inputs)
    const float* W_in_user  = (const float*)d_in[3];
    const float* b_in_user  = (const float*)d_in[4];
    const float* W_in_travel= (const float*)d_in[5];
    const float* b_in_travel= (const float*)d_in[6];
    const float* Wl         = (const float*)d_in[7];
    const float* bl         = (const float*)d_in[8];
    const float* Wr         = (const float*)d_in[9];
    const float* ln_g       = (const float*)d_in[10];
    const float* ln_b       = (const float*)d_in[11];
    // inputs 12..24: expert MLPs (dead) + attn_query/Wq/bq/Wk/bk (dead: softmax over 1 key == 1)
    const float* Wv_        = (const float*)d_in[25];
    const float* bv_        = (const float*)d_in[26];
    const float* Wo_        = (const float*)d_in[27];
    const float* bo_        = (const float*)d_in[28];
    const float* f_ln_g     = (const float*)d_in[29];
    const float* f_ln_b     = (const float*)d_in[30];
    const float* f_W1       = (const float*)d_in[31];
    const float* f_b1       = (const float*)d_in[32];
    const float* f_W2       = (const float*)d_in[33];
    const float* f_b2       = (const float*)d_in[34];
    const int*   ei_ut      = (const int*)d_in[35];
    const int*   ei_tu      = (const int*)d_in[36];
    const int*   ei_tv      = (const int*)d_in[37];
    const int*   ei_vt      = (const int*)d_in[38];
    const int E = in_sizes[35] / 2;

    // ---- workspace layout ----
    char* wsb = (char*)d_ws;
    size_t off = 0;
    auto alloc = [&](size_t bytes) -> void* {
        off = (off + 511) & ~(size_t)511;
        void* p = wsb + off;
        off += bytes;
        return p;
    };
    float* xu   = (float*)alloc((size_t)NU * HD * 4);
    float* xt_a = (float*)alloc((size_t)NT * HD * 4);  // xt_a + xt_b contiguous: reused as
    float* xt_b = (float*)alloc((size_t)NT * HD * 4);  // the NV x 128 attn buffer at the end
    float* Wvo  = (float*)alloc(128 * 128 * 4);
    float* bvo  = (float*)alloc(128 * 4);
    float* WrT  = (float*)alloc((size_t)LAYERS * 128 * 128 * 4);  // Wr[l,0]+Wr[l,3]

    int *rp[4], *cur[4], *colb[4];
    float* invb[4];
    const int ndst[4] = {NU, NT, NT, NV};  // tu, ut, vt, tv
    for (int i = 0; i < 4; ++i) {
        rp[i]   = (int*)alloc((size_t)(ndst[i] + 1) * 4);
        cur[i]  = (int*)alloc((size_t)ndst[i] * 4);
        colb[i] = (int*)alloc((size_t)E * 4);
        invb[i] = (float*)alloc((size_t)ndst[i] * 4);
    }

    auto build_csr = [&](const int* ei, int n_dst, int* rpp, int* curp, int* colp, float* invp) {
        const int* srcA = ei;
        const int* dstA = ei + E;
        hipMemsetAsync(curp, 0, (size_t)n_dst * 4, stream);
        hist_kernel<<<(E + 255) / 256, 256, 0, stream>>>(dstA, curp, E);
        scan_kernel<<<1, 1024, 0, stream>>>(curp, rpp, invp, n_dst);
        scatter_kernel<<<(E + 255) / 256, 256, 0, stream>>>(srcA, dstA, curp, colp, E);
    };
    build_csr(ei_tu, NU, rp[0], cur[0], colb[0], invb[0]);
    build_csr(ei_ut, NT, rp[1], cur[1], colb[1], invb[1]);
    build_csr(ei_vt, NT, rp[2], cur[2], colb[2], invb[2]);
    build_csr(ei_tv, NV, rp[3], cur[3], colb[3], invb[3]);

    addw_kernel<<<LAYERS * 128 * 128 / 256, 256, 0, stream>>>(Wr, WrT);

    // ---- input projections ----
    gemm_kernel<64, false, false><<<NU / 16, 256, 0, stream>>>(
        x_user, W_in_user, b_in_user, xu, nullptr, nullptr);
    gemm_kernel<32, false, false><<<NT / 16, 256, 0, stream>>>(
        x_travel, W_in_travel, b_in_travel, xt_a, nullptr, nullptr);

    // ---- 8 hetero-SAGE layers ----
    constexpr size_t WSZ = 128 * 128;
    float* xt_cur = xt_a;
    float* xt_nxt = xt_b;
    const int nbU = NU / 16, nbV = NV / 16;
    for (int i = 0; i < LAYERS; ++i) {
        const float* Wl_i = Wl + (size_t)i * 4 * WSZ;
        const float* Wr_i = Wr + (size_t)i * 4 * WSZ;
        const float* bl_i = bl + (size_t)i * 4 * 128;
        const float* g_i  = ln_g + (size_t)i * 3 * 128;
        const float* b_i  = ln_b + (size_t)i * 3 * 128;
        // travel: sage(xu via ut, w[0]) + sage(xv via vt, w[3]); runs before xu/xv overwritten
        travel_kernel<<<NT / 16, 256, 0, stream>>>(
            xt_cur, xt_nxt,
            xu, rp[1], colb[1], invb[1], Wl_i + 0 * WSZ, bl_i + 0 * 128,
            xv, rp[2], colb[2], invb[2], Wl_i + 3 * WSZ, bl_i + 3 * 128,
            WrT + (size_t)i * WSZ, g_i + 1 * 128, b_i + 1 * 128);
        // user + visit fused: both read xt_cur only; in-place row-local writes
        UpdParams U = { xu, xu, xt_cur, rp[0], colb[0], invb[0],
                        Wl_i + 1 * WSZ, bl_i + 1 * 128, Wr_i + 1 * WSZ,
                        g_i + 0 * 128, b_i + 0 * 128 };
        UpdParams V = { xv, xv, xt_cur, rp[3], colb[3], invb[3],
                        Wl_i + 2 * WSZ, bl_i + 2 * 128, Wr_i + 2 * WSZ,
                        g_i + 2 * 128, b_i + 2 * 128 };
        uv_kernel<<<nbU + nbV, 256, 0, stream>>>(U, V, nbU);
        float* tmp = xt_cur; xt_cur = xt_nxt; xt_nxt = tmp;
    }

    // ---- head: attn = xv @ (Wv@Wo) + (bv@Wo+bo); z = relu(LN(attn)@W1+b1); out = z@W2+b2 ----
    fold_kernel<<<129, 128, 0, stream>>>(Wv_, bv_, Wo_, bo_, Wvo, bvo);
    float* attn = xt_a;  // xt buffers (contiguous 51.2 MB) are dead now
    gemm_kernel<128, false, false><<<NV / 16, 256, 0, stream>>>(
        xv, Wvo, bvo, attn, nullptr, nullptr);
    gemm_kernel<128, true, true><<<NV / 16, 256, 0, stream>>>(
        attn, f_W1, f_b1, attn, f_ln_g, f_ln_b);
    dot_kernel<<<NV / 4, 256, 0, stream>>>(attn, f_W2, f_b2, (float*)d_out, NV);
}

// Round 4
// 4581.622 us; speedup vs baseline: 1.6662x; 1.1067x over previous
//
#include <hip/hip_runtime.h>

typedef float v4f __attribute__((ext_vector_type(4)));
typedef _Float16 h4 __attribute__((ext_vector_type(4)));
typedef _Float16 h8 __attribute__((ext_vector_type(8)));

namespace {

constexpr int NU = 20000;
constexpr int NT = 50000;
constexpr int NV = 100000;
constexpr int HD = 128;
constexpr int LAYERS = 8;
constexpr float EPS = 1e-5f;
constexpr int CAP = 640;   // staged col indices per CSR per block (16 rows)

__device__ __forceinline__ float wave_sum(float v) {
#pragma unroll
    for (int m = 32; m >= 1; m >>= 1) v += __shfl_xor(v, m, 64);
    return v;
}

// ---------------- batched CSR build (4 edge types, grouped by destination) ----------------

struct CsrJob {
    const int* src; const int* dst;
    int* cur; int* rp; int* col; float* inv;
    int n;
};
struct CsrJobs { CsrJob j[4]; };

__global__ void hist_all_kernel(CsrJobs J, int E, int nbPer) {
    const int which = blockIdx.x / nbPer;
    const int e = (blockIdx.x - which * nbPer) * 256 + threadIdx.x;
    if (e < E) atomicAdd(&J.j[which].cur[J.j[which].dst[e]], 1);
}

__global__ __launch_bounds__(1024) void scan4_kernel(CsrJobs J) {
    __shared__ int sums[1024];
    const CsrJob& job = J.j[blockIdx.x];
    int* deg_cursor = job.cur;
    int* rowptr = job.rp;
    float* inv = job.inv;
    const int n = job.n;
    const int t = threadIdx.x;
    const int chunk = (n + 1023) / 1024;
    const int start = min(t * chunk, n);
    const int end = min(start + chunk, n);
    int s = 0;
    for (int i = start; i < end; ++i) s += deg_cursor[i];
    sums[t] = s;
    __syncthreads();
    for (int off = 1; off < 1024; off <<= 1) {
        int v = (t >= off) ? sums[t - off] : 0;
        __syncthreads();
        sums[t] += v;
        __syncthreads();
    }
    int run = (t == 0) ? 0 : sums[t - 1];
    for (int i = start; i < end; ++i) {
        int d = deg_cursor[i];
        rowptr[i] = run;
        inv[i] = 1.0f / (float)max(d, 1);
        deg_cursor[i] = run;
        run += d;
    }
    if (t == 1023) rowptr[n] = sums[1023];
}

__global__ void scatter_all_kernel(CsrJobs J, int E, int nbPer) {
    const int which = blockIdx.x / nbPer;
    const int e = (blockIdx.x - which * nbPer) * 256 + threadIdx.x;
    if (e < E) {
        const CsrJob& job = J.j[which];
        int p = atomicAdd(&job.cur[job.dst[e]], 1);
        job.col[p] = job.src[e];
    }
}

// ---------------- Wr fold for travel: WrT[l] = Wr[l,0] + Wr[l,3] ----------------

__global__ __launch_bounds__(256) void addw_kernel(const float* __restrict__ Wr,
                                                   float* __restrict__ WrT) {
    int idx = blockIdx.x * 256 + threadIdx.x;       // 8 * 16384
    int layer = idx >> 14, k = idx & 16383;
    WrT[idx] = Wr[(size_t)layer * 4 * 16384 + k] + Wr[(size_t)layer * 4 * 16384 + 3 * 16384 + k];
}

// ---------------- fp32 -> fp16 cast (xv mirror init) ----------------

__global__ __launch_bounds__(256) void cast_kernel(const float* __restrict__ X,
                                                   _Float16* __restrict__ Y, int n4) {
    int i = blockIdx.x * 256 + threadIdx.x;
    if (i < n4) {
        v4f x = *(const v4f*)(X + (size_t)i * 4);
        h4 y;
        y[0] = (_Float16)x.x; y[1] = (_Float16)x.y;
        y[2] = (_Float16)x.z; y[3] = (_Float16)x.w;
        *(h4*)(Y + (size_t)i * 4) = y;
    }
}

// ---------------- per-row gather: mean over CSR neighbors (fp16 payload) ----------------
// Quarter-wave (16 lanes) per row; lane covers 8 cols [c8, c8+8) with ONE 16B load
// per edge. 8-edge unroll -> 8 loads in flight; fp32 accumulation.

#define ACC_H8(vh, X, Y)                                                         \
    {                                                                            \
        X.x += (float)vh[0]; X.y += (float)vh[1];                                \
        X.z += (float)vh[2]; X.w += (float)vh[3];                                \
        Y.x += (float)vh[4]; Y.y += (float)vh[5];                                \
        Y.z += (float)vh[6]; Y.w += (float)vh[7];                                \
    }

__device__ __forceinline__ void gather_row_h(
    const _Float16* __restrict__ src, const int* __restrict__ colg,
    const int* __restrict__ sCol, int off_r, int s0, int e1,
    int c8, float iv, float* __restrict__ outRow) {
    const int d = e1 - s0;
    const int jst = min(d, max(0, CAP - off_r));
    v4f aA = {0.f, 0.f, 0.f, 0.f}, aB = aA, bA = aA, bB = aA;
    int j = 0;
    for (; j + 8 <= jst; j += 8) {
        h8 v0 = *(const h8*)(src + (size_t)sCol[off_r + j + 0] * 128 + c8);
        h8 v1 = *(const h8*)(src + (size_t)sCol[off_r + j + 1] * 128 + c8);
        h8 v2 = *(const h8*)(src + (size_t)sCol[off_r + j + 2] * 128 + c8);
        h8 v3 = *(const h8*)(src + (size_t)sCol[off_r + j + 3] * 128 + c8);
        h8 v4 = *(const h8*)(src + (size_t)sCol[off_r + j + 4] * 128 + c8);
        h8 v5 = *(const h8*)(src + (size_t)sCol[off_r + j + 5] * 128 + c8);
        h8 v6 = *(const h8*)(src + (size_t)sCol[off_r + j + 6] * 128 + c8);
        h8 v7 = *(const h8*)(src + (size_t)sCol[off_r + j + 7] * 128 + c8);
        ACC_H8(v0, aA, aB); ACC_H8(v1, bA, bB);
        ACC_H8(v2, aA, aB); ACC_H8(v3, bA, bB);
        ACC_H8(v4, aA, aB); ACC_H8(v5, bA, bB);
        ACC_H8(v6, aA, aB); ACC_H8(v7, bA, bB);
    }
    for (; j < jst; ++j) {
        h8 v0 = *(const h8*)(src + (size_t)sCol[off_r + j] * 128 + c8);
        ACC_H8(v0, aA, aB);
    }
    for (int e = s0 + jst; e < e1; ++e) {   // overflow fallback (rare)
        h8 v0 = *(const h8*)(src + (size_t)colg[e] * 128 + c8);
        ACC_H8(v0, aA, aB);
    }
    *(v4f*)&outRow[c8] = (aA + bA) * iv;
    *(v4f*)&outRow[c8 + 4] = (aB + bB) * iv;
}

// ---------------- fused SAGE update body ----------------
// out = relu(LN(mean1@Wl1 + bl1 [+ mean2@Wl2 + bl2] + xdst@WrU)) + xdst
// fp32 master in/out, plus fp16 mirror write for next layer's gathers.
// In-place safe (xdst reads are row-local, staged in LDS first).

template <int HAS2>
__device__ __forceinline__ void sage_body(
    int row0, const float* __restrict__ xdst, float* __restrict__ out,
    _Float16* __restrict__ out_h,
    const _Float16* __restrict__ src1, const int* __restrict__ rp1,
    const int* __restrict__ col1, const float* __restrict__ inv1,
    const float* __restrict__ Wl1, const float* __restrict__ bl1,
    const _Float16* __restrict__ src2, const int* __restrict__ rp2,
    const int* __restrict__ col2, const float* __restrict__ inv2,
    const float* __restrict__ Wl2, const float* __restrict__ bl2,
    const float* __restrict__ WrU,
    const float* __restrict__ g, const float* __restrict__ bln,
    float* sA1, float* sXd, float* sA2, int* sC1, int* sC2) {
    const int t = threadIdx.x;
    const int w = t >> 6, l = t & 63;

    for (int idx = t; idx < 2048; idx += 256)
        sXd[idx] = xdst[(size_t)row0 * 128 + idx];

    const int eb1 = rp1[row0];
    const int cnt1 = min(rp1[row0 + 16] - eb1, CAP);
    for (int i = t; i < cnt1; i += 256) sC1[i] = col1[eb1 + i];
    int eb2 = 0;
    if constexpr (HAS2) {
        eb2 = rp2[row0];
        const int cnt2 = min(rp2[row0 + 16] - eb2, CAP);
        for (int i = t; i < cnt2; i += 256) sC2[i] = col2[eb2 + i];
    }
    __syncthreads();

    // Phase A: gather (fp16 payload, fp32 accumulate)
    const int rq = (w << 2) | (l >> 4);
    const int c8 = (l & 15) * 8;
    const int grq = row0 + rq;
    {
        const int s0 = rp1[grq], e1 = rp1[grq + 1];
        gather_row_h(src1, col1, sC1, s0 - eb1, s0, e1, c8, inv1[grq], &sA1[rq * 128]);
    }
    if constexpr (HAS2) {
        const int s0 = rp2[grq], e1 = rp2[grq + 1];
        gather_row_h(src2, col2, sC2, s0 - eb2, s0, e1, c8, inv2[grq], &sA2[rq * 128]);
    }
    __syncthreads();

    // Phase B: register-tiled fp32 GEMM, 2 rows x 4 cols per thread
    const int c0 = (t & 31) * 4;
    const int r0 = (t >> 5) * 2;
    v4f bias = *(const v4f*)&bl1[c0];
    if constexpr (HAS2) bias += *(const v4f*)&bl2[c0];
    v4f acc0 = bias, acc1 = bias;
#pragma unroll 2
    for (int k = 0; k < 128; k += 4) {
        {
            v4f a0 = *(const v4f*)&sA1[r0 * 128 + k];
            v4f a1 = *(const v4f*)&sA1[(r0 + 1) * 128 + k];
            v4f w0 = *(const v4f*)&Wl1[(k + 0) * 128 + c0];
            v4f w1 = *(const v4f*)&Wl1[(k + 1) * 128 + c0];
            v4f w2 = *(const v4f*)&Wl1[(k + 2) * 128 + c0];
            v4f w3 = *(const v4f*)&Wl1[(k + 3) * 128 + c0];
            acc0 += a0.x * w0 + a0.y * w1 + a0.z * w2 + a0.w * w3;
            acc1 += a1.x * w0 + a1.y * w1 + a1.z * w2 + a1.w * w3;
        }
        if constexpr (HAS2) {
            v4f a0 = *(const v4f*)&sA2[r0 * 128 + k];
            v4f a1 = *(const v4f*)&sA2[(r0 + 1) * 128 + k];
            v4f w0 = *(const v4f*)&Wl2[(k + 0) * 128 + c0];
            v4f w1 = *(const v4f*)&Wl2[(k + 1) * 128 + c0];
            v4f w2 = *(const v4f*)&Wl2[(k + 2) * 128 + c0];
            v4f w3 = *(const v4f*)&Wl2[(k + 3) * 128 + c0];
            acc0 += a0.x * w0 + a0.y * w1 + a0.z * w2 + a0.w * w3;
            acc1 += a1.x * w0 + a1.y * w1 + a1.z * w2 + a1.w * w3;
        }
        {
            v4f x0 = *(const v4f*)&sXd[r0 * 128 + k];
            v4f x1 = *(const v4f*)&sXd[(r0 + 1) * 128 + k];
            v4f u0 = *(const v4f*)&WrU[(k + 0) * 128 + c0];
            v4f u1 = *(const v4f*)&WrU[(k + 1) * 128 + c0];
            v4f u2 = *(const v4f*)&WrU[(k + 2) * 128 + c0];
            v4f u3 = *(const v4f*)&WrU[(k + 3) * 128 + c0];
            acc0 += x0.x * u0 + x0.y * u1 + x0.z * u2 + x0.w * u3;
            acc1 += x1.x * u0 + x1.y * u1 + x1.z * u2 + x1.w * u3;
        }
    }
    __syncthreads();
    *(v4f*)&sA1[r0 * 128 + c0] = acc0;        // h overwrites agg1
    *(v4f*)&sA1[(r0 + 1) * 128 + c0] = acc1;
    __syncthreads();

    // Phase C: LayerNorm + ReLU + residual; fp32 + fp16 mirror stores
    for (int q = 0; q < 4; ++q) {
        const int r = w * 4 + q;
        const size_t gr = (size_t)(row0 + r);
        float h0 = sA1[r * 128 + l], h1 = sA1[r * 128 + 64 + l];
        float m = wave_sum(h0 + h1) * (1.0f / 128.0f);
        float d0 = h0 - m, d1 = h1 - m;
        float var = wave_sum(d0 * d0 + d1 * d1) * (1.0f / 128.0f);
        float rs = rsqrtf(var + EPS);
        float y0 = fmaxf(d0 * rs * g[l] + bln[l], 0.f) + sXd[r * 128 + l];
        float y1 = fmaxf(d1 * rs * g[64 + l] + bln[64 + l], 0.f) + sXd[r * 128 + 64 + l];
        out[gr * 128 + l] = y0;
        out[gr * 128 + 64 + l] = y1;
        out_h[gr * 128 + l] = (_Float16)y0;
        out_h[gr * 128 + 64 + l] = (_Float16)y1;
    }
}

struct UpdParams {
    const float* xdst; float* out; _Float16* out_h;
    const _Float16* srch; const int* rp; const int* col; const float* inv;
    const float* Wl; const float* bl; const float* Wr;
    const float* g; const float* bln;
};

__global__ __launch_bounds__(256, 4) void travel_kernel(
    const float* xdst, float* out, _Float16* out_h,
    const _Float16* src1, const int* rp1, const int* col1, const float* inv1,
    const float* Wl1, const float* bl1,
    const _Float16* src2, const int* rp2, const int* col2, const float* inv2,
    const float* Wl2, const float* bl2,
    const float* WrT, const float* g, const float* bln) {
    __shared__ __align__(16) float sA1[2048];
    __shared__ __align__(16) float sXd[2048];
    __shared__ __align__(16) float sA2[2048];
    __shared__ int sC1[CAP];
    __shared__ int sC2[CAP];
    sage_body<1>(blockIdx.x * 16, xdst, out, out_h,
                 src1, rp1, col1, inv1, Wl1, bl1,
                 src2, rp2, col2, inv2, Wl2, bl2,
                 WrT, g, bln, sA1, sXd, sA2, sC1, sC2);
}

__global__ __launch_bounds__(256, 4) void uv_kernel(UpdParams U, UpdParams V, int nbU) {
    __shared__ __align__(16) float sA1[2048];
    __shared__ __align__(16) float sXd[2048];
    __shared__ int sC1[CAP];
    const bool isU = (int)blockIdx.x < nbU;
    const UpdParams& P = isU ? U : V;
    const int row0 = (isU ? blockIdx.x : blockIdx.x - nbU) * 16;
    sage_body<0>(row0, P.xdst, P.out, P.out_h,
                 P.srch, P.rp, P.col, P.inv, P.Wl, P.bl,
                 nullptr, nullptr, nullptr, nullptr, nullptr, nullptr,
                 P.Wr, P.g, P.bln, sA1, sXd, nullptr, sC1, nullptr);
}

// ---------------- generic Y[n x 128] = act(LN?(X[n x K]) @ W + b), optional fp16 mirror ----------------

template <int K, bool LN_IN, bool RELU, bool MIRROR>
__global__ __launch_bounds__(256) void gemm_kernel(const float* __restrict__ X,
                                                   const float* __restrict__ W,
                                                   const float* __restrict__ bias,
                                                   float* __restrict__ Y,
                                                   _Float16* __restrict__ Yh,
                                                   const float* __restrict__ g,
                                                   const float* __restrict__ bln) {
    static_assert(!LN_IN || K == 128, "LN input requires K==128");
    __shared__ __align__(16) float As[16 * K];
    const int t = threadIdx.x;
    const size_t row0 = (size_t)blockIdx.x * 16;

    for (int idx = t; idx < 16 * K; idx += 256) As[idx] = X[row0 * K + idx];
    __syncthreads();

    if (LN_IN) {
        const int w = t >> 6, l = t & 63;
        for (int q = 0; q < 4; ++q) {
            const int r = w * 4 + q;
            float a0 = As[r * K + l], a1 = As[r * K + 64 + l];
            float m = wave_sum(a0 + a1) * (1.0f / 128.0f);
            float d0 = a0 - m, d1 = a1 - m;
            float var = wave_sum(d0 * d0 + d1 * d1) * (1.0f / 128.0f);
            float rs = rsqrtf(var + EPS);
            As[r * K + l] = d0 * rs * g[l] + bln[l];
            As[r * K + 64 + l] = d1 * rs * g[64 + l] + bln[64 + l];
        }
        __syncthreads();
    }

    const int c0 = (t & 31) * 4;
    const int r0 = (t >> 5) * 2;
    v4f b4 = *(const v4f*)&bias[c0];
    v4f acc0 = b4, acc1 = b4;
#pragma unroll 4
    for (int k = 0; k < K; k += 4) {
        v4f a0 = *(const v4f*)&As[r0 * K + k];
        v4f a1 = *(const v4f*)&As[(r0 + 1) * K + k];
        v4f w0 = *(const v4f*)&W[(size_t)(k + 0) * HD + c0];
        v4f w1 = *(const v4f*)&W[(size_t)(k + 1) * HD + c0];
        v4f w2 = *(const v4f*)&W[(size_t)(k + 2) * HD + c0];
        v4f w3 = *(const v4f*)&W[(size_t)(k + 3) * HD + c0];
        acc0 += a0.x * w0 + a0.y * w1 + a0.z * w2 + a0.w * w3;
        acc1 += a1.x * w0 + a1.y * w1 + a1.z * w2 + a1.w * w3;
    }
    if (RELU) {
#pragma unroll
        for (int i = 0; i < 4; ++i) {
            acc0[i] = fmaxf(acc0[i], 0.0f);
            acc1[i] = fmaxf(acc1[i], 0.0f);
        }
    }
    *(v4f*)&Y[(row0 + r0) * HD + c0] = acc0;
    *(v4f*)&Y[(row0 + r0 + 1) * HD + c0] = acc1;
    if (MIRROR) {
        h4 m0, m1;
#pragma unroll
        for (int i = 0; i < 4; ++i) {
            m0[i] = (_Float16)acc0[i];
            m1[i] = (_Float16)acc1[i];
        }
        *(h4*)&Yh[(row0 + r0) * HD + c0] = m0;
        *(h4*)&Yh[(row0 + r0 + 1) * HD + c0] = m1;
    }
}

// ---------------- attention-gate weight folding: Wvo = Wv@Wo, bvo = bv@Wo + bo ----------------

__global__ __launch_bounds__(128) void fold_kernel(const float* __restrict__ Wv,
                                                   const float* __restrict__ bv,
                                                   const float* __restrict__ Wo,
                                                   const float* __restrict__ bo,
                                                   float* __restrict__ Wvo,
                                                   float* __restrict__ bvo) {
    const int c = threadIdx.x;
    const int r = blockIdx.x;
    if (r < 128) {
        float s = 0.f;
        for (int k = 0; k < 128; ++k) s += Wv[r * 128 + k] * Wo[k * 128 + c];
        Wvo[r * 128 + c] = s;
    } else {
        float s = bo[c];
        for (int k = 0; k < 128; ++k) s += bv[k] * Wo[k * 128 + c];
        bvo[c] = s;
    }
}

// ---------------- out[r] = dot(z[r], w2) + b2 ----------------

__global__ __launch_bounds__(256) void dot_kernel(const float* __restrict__ Z,
                                                  const float* __restrict__ w2,
                                                  const float* __restrict__ b2,
                                                  float* __restrict__ out, int n) {
    const int w = threadIdx.x >> 6, l = threadIdx.x & 63;
    const size_t row = (size_t)blockIdx.x * 4 + w;
    if (row < (size_t)n) {
        float v = Z[row * 128 + l] * w2[l] + Z[row * 128 + 64 + l] * w2[64 + l];
        v = wave_sum(v);
        if (l == 0) out[row] = v + b2[0];
    }
}

}  // namespace

extern "C" void kernel_launch(void* const* d_in, const int* in_sizes, int n_in,
                              void* d_out, int out_size, void* d_ws, size_t ws_size,
                              hipStream_t stream) {
    const float* x_user     = (const float*)d_in[0];
    const float* x_travel   = (const float*)d_in[1];
    float*       xv         = (float*)d_in[2];   // updated in place (harness restores inputs)
    const float* W_in_user  = (const float*)d_in[3];
    const float* b_in_user  = (const float*)d_in[4];
    const float* W_in_travel= (const float*)d_in[5];
    const float* b_in_travel= (const float*)d_in[6];
    const float* Wl         = (const float*)d_in[7];
    const float* bl         = (const float*)d_in[8];
    const float* Wr         = (const float*)d_in[9];
    const float* ln_g       = (const float*)d_in[10];
    const float* ln_b       = (const float*)d_in[11];
    // inputs 12..24: expert MLPs (dead) + attn_query/Wq/bq/Wk/bk (dead: softmax over 1 key == 1)
    const float* Wv_        = (const float*)d_in[25];
    const float* bv_        = (const float*)d_in[26];
    const float* Wo_        = (const float*)d_in[27];
    const float* bo_        = (const float*)d_in[28];
    const float* f_ln_g     = (const float*)d_in[29];
    const float* f_ln_b     = (const float*)d_in[30];
    const float* f_W1       = (const float*)d_in[31];
    const float* f_b1       = (const float*)d_in[32];
    const float* f_W2       = (const float*)d_in[33];
    const float* f_b2       = (const float*)d_in[34];
    const int*   ei_ut      = (const int*)d_in[35];
    const int*   ei_tu      = (const int*)d_in[36];
    const int*   ei_tv      = (const int*)d_in[37];
    const int*   ei_vt      = (const int*)d_in[38];
    const int E = in_sizes[35] / 2;

    // ---- workspace layout (~103 MB) ----
    char* wsb = (char*)d_ws;
    size_t off = 0;
    auto alloc = [&](size_t bytes) -> void* {
        off = (off + 511) & ~(size_t)511;
        void* p = wsb + off;
        off += bytes;
        return p;
    };
    float* xu   = (float*)alloc((size_t)NU * HD * 4);
    float* xt   = (float*)alloc((size_t)NT * HD * 4);     // single fp32 buffer (in-place)
    // fp16 mirrors, contiguous (region reused as the NV x 128 fp32 attn buffer at head)
    _Float16* xu_h  = (_Float16*)alloc((size_t)NU * HD * 2);
    _Float16* xv_h  = (_Float16*)alloc((size_t)NV * HD * 2);
    _Float16* xt_h0 = (_Float16*)alloc((size_t)NT * HD * 2);
    _Float16* xt_h1 = (_Float16*)alloc((size_t)NT * HD * 2);
    float* Wvo  = (float*)alloc(128 * 128 * 4);
    float* bvo  = (float*)alloc(128 * 4);
    float* WrT  = (float*)alloc((size_t)LAYERS * 128 * 128 * 4);  // Wr[l,0]+Wr[l,3]

    const int ndst[4] = {NU, NT, NT, NV};  // tu, ut, vt, tv
    int* cur4 = (int*)alloc((size_t)(NU + NT + NT + NV) * 4);
    int *rp[4], *colb[4];
    float* invb[4];
    int* cur[4];
    {
        int coff = 0;
        for (int i = 0; i < 4; ++i) {
            cur[i] = cur4 + coff;
            coff += ndst[i];
            rp[i]   = (int*)alloc((size_t)(ndst[i] + 1) * 4);
            colb[i] = (int*)alloc((size_t)E * 4);
            invb[i] = (float*)alloc((size_t)ndst[i] * 4);
        }
    }

    // ---- batched CSR build: 1 memset + 3 launches ----
    hipMemsetAsync(cur4, 0, (size_t)(NU + NT + NT + NV) * 4, stream);
    CsrJobs J;
    J.j[0] = { ei_tu, ei_tu + E, cur[0], rp[0], colb[0], invb[0], NU };
    J.j[1] = { ei_ut, ei_ut + E, cur[1], rp[1], colb[1], invb[1], NT };
    J.j[2] = { ei_vt, ei_vt + E, cur[2], rp[2], colb[2], invb[2], NT };
    J.j[3] = { ei_tv, ei_tv + E, cur[3], rp[3], colb[3], invb[3], NV };
    const int nbPer = (E + 255) / 256;
    hist_all_kernel<<<4 * nbPer, 256, 0, stream>>>(J, E, nbPer);
    scan4_kernel<<<4, 1024, 0, stream>>>(J);
    scatter_all_kernel<<<4 * nbPer, 256, 0, stream>>>(J, E, nbPer);

    addw_kernel<<<LAYERS * 128 * 128 / 256, 256, 0, stream>>>(Wr, WrT);

    // ---- input projections (+ fp16 mirrors) ----
    gemm_kernel<64, false, false, true><<<NU / 16, 256, 0, stream>>>(
        x_user, W_in_user, b_in_user, xu, xu_h, nullptr, nullptr);
    gemm_kernel<32, false, false, true><<<NT / 16, 256, 0, stream>>>(
        x_travel, W_in_travel, b_in_travel, xt, xt_h0, nullptr, nullptr);
    cast_kernel<<<(NV * HD / 4 + 255) / 256, 256, 0, stream>>>(xv, xv_h, NV * HD / 4);

    // ---- 8 hetero-SAGE layers ----
    constexpr size_t WSZ = 128 * 128;
    const int nbU = NU / 16;
    for (int i = 0; i < LAYERS; ++i) {
        const float* Wl_i = Wl + (size_t)i * 4 * WSZ;
        const float* Wr_i = Wr + (size_t)i * 4 * WSZ;
        const float* bl_i = bl + (size_t)i * 4 * 128;
        const float* g_i  = ln_g + (size_t)i * 3 * 128;
        const float* b_i  = ln_b + (size_t)i * 3 * 128;
        _Float16* xth_cur = (i & 1) ? xt_h1 : xt_h0;
        _Float16* xth_nxt = (i & 1) ? xt_h0 : xt_h1;
        // travel: gathers xu_h (ut, w[0]) + xv_h (vt, w[3]); fp32 xt updated in place
        // (row-local); OLD xt stays visible to uv via the xth_cur mirror.
        travel_kernel<<<NT / 16, 256, 0, stream>>>(
            xt, xt, xth_nxt,
            xu_h, rp[1], colb[1], invb[1], Wl_i + 0 * WSZ, bl_i + 0 * 128,
            xv_h, rp[2], colb[2], invb[2], Wl_i + 3 * WSZ, bl_i + 3 * 128,
            WrT + (size_t)i * WSZ, g_i + 1 * 128, b_i + 1 * 128);
        // user + visit fused: both gather OLD xt via xth_cur; in-place row-local writes
        UpdParams U = { xu, xu, xu_h, xth_cur, rp[0], colb[0], invb[0],
                        Wl_i + 1 * WSZ, bl_i + 1 * 128, Wr_i + 1 * WSZ,
                        g_i + 0 * 128, b_i + 0 * 128 };
        UpdParams V = { xv, xv, xv_h, xth_cur, rp[3], colb[3], invb[3],
                        Wl_i + 2 * WSZ, bl_i + 2 * 128, Wr_i + 2 * WSZ,
                        g_i + 2 * 128, b_i + 2 * 128 };
        uv_kernel<<<nbU + NV / 16, 256, 0, stream>>>(U, V, nbU);
    }

    // ---- head: attn = xv @ (Wv@Wo) + (bv@Wo+bo); z = relu(LN(attn)@W1+b1); out = z@W2+b2 ----
    fold_kernel<<<129, 128, 0, stream>>>(Wv_, bv_, Wo_, bo_, Wvo, bvo);
    float* attn = (float*)xu_h;  // mirror region (56.3 MB contiguous) is dead at head time
    gemm_kernel<128, false, false, false><<<NV / 16, 256, 0, stream>>>(
        xv, Wvo, bvo, attn, nullptr, nullptr, nullptr);
    gemm_kernel<128, true, true, false><<<NV / 16, 256, 0, stream>>>(
        attn, f_W1, f_b1, attn, nullptr, f_ln_g, f_ln_b);
    dot_kernel<<<NV / 4, 256, 0, stream>>>(attn, f_W2, f_b2, (float*)d_out, NV);
}

// Round 5
// 2698.136 us; speedup vs baseline: 2.8293x; 1.6981x over previous
//
#include <hip/hip_runtime.h>

typedef float v4f __attribute__((ext_vector_type(4)));
typedef _Float16 h4 __attribute__((ext_vector_type(4)));
typedef _Float16 h8 __attribute__((ext_vector_type(8)));

namespace {

constexpr int NU = 20000;
constexpr int NT = 50000;
constexpr int NV = 100000;
constexpr int HD = 128;
constexpr int LAYERS = 8;
constexpr float EPS = 1e-5f;

// padded row counts (multiples of 64) for fp16 mirrors
constexpr int NUP = 20032, NTP = 50048, NVP = 100032;

constexpr int AGS = 136;   // aggH fp16 row stride (16B-aligned: 272B)
constexpr int HBS = 132;   // hbuf fp32 row stride (16B-aligned: 528B, bank-spread)

__device__ __forceinline__ float wave_sum(float v) {
#pragma unroll
    for (int m = 32; m >= 1; m >>= 1) v += __shfl_xor(v, m, 64);
    return v;
}
__device__ __forceinline__ float qsum16(float v) {   // reduce within 16-lane group
#pragma unroll
    for (int m = 8; m >= 1; m >>= 1) v += __shfl_xor(v, m, 64);
    return v;
}

// ---------------- batched CSR build ----------------

struct CsrJob {
    const int* src; const int* dst;
    int* cur; int* rp; int* col; float* inv;
    int n;
};
struct CsrJobs { CsrJob j[4]; };

__global__ void hist_all_kernel(CsrJobs J, int E, int nbPer) {
    const int which = blockIdx.x / nbPer;
    const int e = (blockIdx.x - which * nbPer) * 256 + threadIdx.x;
    if (e < E) atomicAdd(&J.j[which].cur[J.j[which].dst[e]], 1);
}

__global__ __launch_bounds__(1024) void scan4_kernel(CsrJobs J) {
    __shared__ int sums[1024];
    const CsrJob& job = J.j[blockIdx.x];
    int* deg_cursor = job.cur;
    int* rowptr = job.rp;
    float* inv = job.inv;
    const int n = job.n;
    const int t = threadIdx.x;
    const int chunk = (n + 1023) / 1024;
    const int start = min(t * chunk, n);
    const int end = min(start + chunk, n);
    int s = 0;
    for (int i = start; i < end; ++i) s += deg_cursor[i];
    sums[t] = s;
    __syncthreads();
    for (int off = 1; off < 1024; off <<= 1) {
        int v = (t >= off) ? sums[t - off] : 0;
        __syncthreads();
        sums[t] += v;
        __syncthreads();
    }
    int run = (t == 0) ? 0 : sums[t - 1];
    for (int i = start; i < end; ++i) {
        int d = deg_cursor[i];
        rowptr[i] = run;
        inv[i] = 1.0f / (float)max(d, 1);
        deg_cursor[i] = run;
        run += d;
    }
    if (t == 1023) rowptr[n] = sums[1023];
}

__global__ void scatter_all_kernel(CsrJobs J, int E, int nbPer) {
    const int which = blockIdx.x / nbPer;
    const int e = (blockIdx.x - which * nbPer) * 256 + threadIdx.x;
    if (e < E) {
        const CsrJob& job = J.j[which];
        int p = atomicAdd(&job.cur[job.dst[e]], 1);
        job.col[p] = job.src[e];
    }
}

// ---------------- transpose+cast weights to fp16 W^T ----------------
// slot = layer*7 + j; j=0..3: Wl[layer][j]^T; j=4: (Wr[l][0]+Wr[l][3])^T;
// j=5: Wr[l][1]^T; j=6: Wr[l][2]^T.  WT[slot][n][k] (row-major 128x128 fp16)

__global__ __launch_bounds__(256) void tw_kernel(const float* __restrict__ Wl,
                                                 const float* __restrict__ Wr,
                                                 _Float16* __restrict__ WT) {
    const int slot = blockIdx.x;
    const int layer = slot / 7, j = slot % 7;
    const float* A;
    const float* B = nullptr;
    if (j < 4) A = Wl + ((size_t)layer * 4 + j) * 16384;
    else if (j == 4) {
        A = Wr + ((size_t)layer * 4 + 0) * 16384;
        B = Wr + ((size_t)layer * 4 + 3) * 16384;
    } else A = Wr + ((size_t)layer * 4 + (j - 4)) * 16384;
    _Float16* o = WT + (size_t)slot * 16384;
    for (int idx = threadIdx.x; idx < 16384; idx += 256) {
        const int n = idx >> 7, k = idx & 127;
        float v = A[k * 128 + n];
        if (j == 4) v += B[k * 128 + n];
        o[idx] = (_Float16)v;
    }
}

// ---------------- fp32 -> fp16 cast (xv mirror init) ----------------

__global__ __launch_bounds__(256) void cast_kernel(const float* __restrict__ X,
                                                   _Float16* __restrict__ Y, int n4) {
    int i = blockIdx.x * 256 + threadIdx.x;
    if (i < n4) {
        v4f x = *(const v4f*)(X + (size_t)i * 4);
        h4 y;
        y[0] = (_Float16)x.x; y[1] = (_Float16)x.y;
        y[2] = (_Float16)x.z; y[3] = (_Float16)x.w;
        *(h4*)(Y + (size_t)i * 4) = y;
    }
}

// ---------------- per-row gather into fp16 LDS (MFMA A layout source) ----------------

#define ACC_H8(vh, X, Y)                                                         \
    {                                                                            \
        X.x += (float)vh[0]; X.y += (float)vh[1];                                \
        X.z += (float)vh[2]; X.w += (float)vh[3];                                \
        Y.x += (float)vh[4]; Y.y += (float)vh[5];                                \
        Y.z += (float)vh[6]; Y.w += (float)vh[7];                                \
    }

__device__ __forceinline__ void gather_row_h(
    const _Float16* __restrict__ src, const int* __restrict__ colg,
    const int* __restrict__ sCol, int off_r, int s0, int e1,
    int c8, float iv, _Float16* __restrict__ outRow, int cap) {
    const int d = e1 - s0;
    const int jst = min(d, max(0, cap - off_r));
    v4f aA = {0.f, 0.f, 0.f, 0.f}, aB = aA, bA = aA, bB = aA;
    int j = 0;
    for (; j + 8 <= jst; j += 8) {
        h8 v0 = *(const h8*)(src + (size_t)sCol[off_r + j + 0] * 128 + c8);
        h8 v1 = *(const h8*)(src + (size_t)sCol[off_r + j + 1] * 128 + c8);
        h8 v2 = *(const h8*)(src + (size_t)sCol[off_r + j + 2] * 128 + c8);
        h8 v3 = *(const h8*)(src + (size_t)sCol[off_r + j + 3] * 128 + c8);
        h8 v4 = *(const h8*)(src + (size_t)sCol[off_r + j + 4] * 128 + c8);
        h8 v5 = *(const h8*)(src + (size_t)sCol[off_r + j + 5] * 128 + c8);
        h8 v6 = *(const h8*)(src + (size_t)sCol[off_r + j + 6] * 128 + c8);
        h8 v7 = *(const h8*)(src + (size_t)sCol[off_r + j + 7] * 128 + c8);
        ACC_H8(v0, aA, aB); ACC_H8(v1, bA, bB);
        ACC_H8(v2, aA, aB); ACC_H8(v3, bA, bB);
        ACC_H8(v4, aA, aB); ACC_H8(v5, bA, bB);
        ACC_H8(v6, aA, aB); ACC_H8(v7, bA, bB);
    }
    for (; j < jst; ++j) {
        h8 v0 = *(const h8*)(src + (size_t)sCol[off_r + j] * 128 + c8);
        ACC_H8(v0, aA, aB);
    }
    for (int e = s0 + jst; e < e1; ++e) {   // overflow fallback (rare)
        h8 v0 = *(const h8*)(src + (size_t)colg[e] * 128 + c8);
        ACC_H8(v0, aA, aB);
    }
    v4f r0 = (aA + bA) * iv;
    v4f r1 = (aB + bB) * iv;
    h8 o;
    o[0] = (_Float16)r0.x; o[1] = (_Float16)r0.y; o[2] = (_Float16)r0.z; o[3] = (_Float16)r0.w;
    o[4] = (_Float16)r1.x; o[5] = (_Float16)r1.y; o[6] = (_Float16)r1.z; o[7] = (_Float16)r1.w;
    *(h8*)(outRow + c8) = o;
}

// ---------------- MFMA SAGE update body ----------------
// Block = 256 threads = 4 waves, 64 rows. Wave w owns rows [w*16, w*16+16).
// out = relu(LN(agg1@Wl1 + [agg2@Wl2] + xdst@Wr + bias)) + xdst(fp32)
// A-fragments: agg from LDS fp16; xdst from fp16 mirror (global).
// B-fragments: fp16 W^T from global (L2-hot). Verified layouts:
//   A[m=lane&15][k=quad*8+j], B[k=quad*8+j][n=lane&15], C/D row=quad*4+reg, col=lane&15.

template <int HAS2>
__device__ __forceinline__ void sage_mfma_body(
    int row0, int nrows,
    const float* __restrict__ xdst, float* __restrict__ out,
    _Float16* __restrict__ out_h, const _Float16* __restrict__ xdh,
    const _Float16* __restrict__ src1h, const int* __restrict__ rp1,
    const int* __restrict__ col1, const float* __restrict__ inv1,
    const _Float16* __restrict__ Wl1T, const float* __restrict__ bl1,
    const _Float16* __restrict__ src2h, const int* __restrict__ rp2,
    const int* __restrict__ col2, const float* __restrict__ inv2,
    const _Float16* __restrict__ Wl2T, const float* __restrict__ bl2,
    const _Float16* __restrict__ WrTh,
    const float* __restrict__ g, const float* __restrict__ bln,
    _Float16* aggH1, _Float16* aggH2, float* hbuf, int* sC1, int* sC2, int cap) {
    const int t = threadIdx.x;
    const int w = t >> 6, l = t & 63;
    const int m = l & 15, q = l >> 4;
    const int c8 = m * 8;
    const int rows_end = min(row0 + 64, nrows);

    // stage col indices (block-cooperative)
    const int eb1 = rp1[row0];
    const int cnt1 = min(rp1[rows_end] - eb1, cap);
    for (int i = t; i < cnt1; i += 256) sC1[i] = col1[eb1 + i];
    int eb2 = 0;
    if constexpr (HAS2) {
        eb2 = rp2[row0];
        const int cnt2 = min(rp2[rows_end] - eb2, cap);
        for (int i = t; i < cnt2; i += 256) sC2[i] = col2[eb2 + i];
    }
    __syncthreads();

    // Phase A: gather (quarter-wave per row, 4 rows each)
#pragma unroll
    for (int i = 0; i < 4; ++i) {
        const int rloc = w * 16 + q * 4 + i;
        const int gr = row0 + rloc;
        if (gr < nrows) {
            {
                const int s0 = rp1[gr], e1r = rp1[gr + 1];
                gather_row_h(src1h, col1, sC1, s0 - eb1, s0, e1r, c8, inv1[gr],
                             aggH1 + (size_t)rloc * AGS, cap);
            }
            if constexpr (HAS2) {
                const int s0 = rp2[gr], e1r = rp2[gr + 1];
                gather_row_h(src2h, col2, sC2, s0 - eb2, s0, e1r, c8, inv2[gr],
                             aggH2 + (size_t)rloc * AGS, cap);
            }
        }
    }

    // Phase B: MFMA. acc[nt] covers cols [nt*16, nt*16+16), rows w*16+q*4+reg.
    v4f acc[8];
#pragma unroll
    for (int nt = 0; nt < 8; ++nt) acc[nt] = (v4f){0.f, 0.f, 0.f, 0.f};

    // xdst term (fp16 mirror, no LDS dependency)
    const _Float16* xdrow = xdh + (size_t)(row0 + w * 16 + m) * 128;
#pragma unroll
    for (int kt = 0; kt < 4; ++kt) {
        h8 a = *(const h8*)(xdrow + kt * 32 + q * 8);
#pragma unroll
        for (int nt = 0; nt < 8; ++nt) {
            h8 b = *(const h8*)(WrTh + (size_t)(nt * 16 + m) * 128 + kt * 32 + q * 8);
            acc[nt] = __builtin_amdgcn_mfma_f32_16x16x32_f16(a, b, acc[nt], 0, 0, 0);
        }
    }
    __syncthreads();   // aggH writes visible / ordered

    const _Float16* arow1 = aggH1 + (size_t)(w * 16 + m) * AGS;
#pragma unroll
    for (int kt = 0; kt < 4; ++kt) {
        h8 a = *(const h8*)(arow1 + kt * 32 + q * 8);
#pragma unroll
        for (int nt = 0; nt < 8; ++nt) {
            h8 b = *(const h8*)(Wl1T + (size_t)(nt * 16 + m) * 128 + kt * 32 + q * 8);
            acc[nt] = __builtin_amdgcn_mfma_f32_16x16x32_f16(a, b, acc[nt], 0, 0, 0);
        }
    }
    if constexpr (HAS2) {
        const _Float16* arow2 = aggH2 + (size_t)(w * 16 + m) * AGS;
#pragma unroll
        for (int kt = 0; kt < 4; ++kt) {
            h8 a = *(const h8*)(arow2 + kt * 32 + q * 8);
#pragma unroll
            for (int nt = 0; nt < 8; ++nt) {
                h8 b = *(const h8*)(Wl2T + (size_t)(nt * 16 + m) * 128 + kt * 32 + q * 8);
                acc[nt] = __builtin_amdgcn_mfma_f32_16x16x32_f16(a, b, acc[nt], 0, 0, 0);
            }
        }
    }
    __syncthreads();   // all agg reads done before hbuf (aliased) overwrites

    // acc -> hbuf (layout transform for coalesced epilogue)
#pragma unroll
    for (int nt = 0; nt < 8; ++nt)
#pragma unroll
        for (int r = 0; r < 4; ++r)
            hbuf[(size_t)(w * 16 + q * 4 + r) * HBS + nt * 16 + m] = acc[nt][r];
    __syncthreads();

    // Phase C: bias + LayerNorm + ReLU + fp32 residual; fp32 + fp16 mirror stores
    v4f bg0 = *(const v4f*)&bl1[c8];
    v4f bg1 = *(const v4f*)&bl1[c8 + 4];
    if constexpr (HAS2) {
        bg0 += *(const v4f*)&bl2[c8];
        bg1 += *(const v4f*)&bl2[c8 + 4];
    }
    v4f g0 = *(const v4f*)&g[c8], g1 = *(const v4f*)&g[c8 + 4];
    v4f lb0 = *(const v4f*)&bln[c8], lb1 = *(const v4f*)&bln[c8 + 4];
#pragma unroll
    for (int i = 0; i < 4; ++i) {
        const int rloc = w * 16 + q * 4 + i;
        const int gr = row0 + rloc;
        if (gr >= nrows) continue;
        v4f h0 = *(const v4f*)&hbuf[(size_t)rloc * HBS + c8] + bg0;
        v4f h1 = *(const v4f*)&hbuf[(size_t)rloc * HBS + c8 + 4] + bg1;
        float part = h0.x + h0.y + h0.z + h0.w + h1.x + h1.y + h1.z + h1.w;
        float mean = qsum16(part) * (1.0f / 128.0f);
        v4f d0 = h0 - mean, d1 = h1 - mean;
        float vp = d0.x * d0.x + d0.y * d0.y + d0.z * d0.z + d0.w * d0.w +
                   d1.x * d1.x + d1.y * d1.y + d1.z * d1.z + d1.w * d1.w;
        float var = qsum16(vp) * (1.0f / 128.0f);
        float rs = rsqrtf(var + EPS);
        v4f x0 = *(const v4f*)&xdst[(size_t)gr * 128 + c8];
        v4f x1 = *(const v4f*)&xdst[(size_t)gr * 128 + c8 + 4];
        v4f y0, y1;
#pragma unroll
        for (int e = 0; e < 4; ++e) {
            y0[e] = fmaxf(d0[e] * rs * g0[e] + lb0[e], 0.f) + x0[e];
            y1[e] = fmaxf(d1[e] * rs * g1[e] + lb1[e], 0.f) + x1[e];
        }
        *(v4f*)&out[(size_t)gr * 128 + c8] = y0;
        *(v4f*)&out[(size_t)gr * 128 + c8 + 4] = y1;
        h8 oh;
#pragma unroll
        for (int e = 0; e < 4; ++e) {
            oh[e] = (_Float16)y0[e];
            oh[4 + e] = (_Float16)y1[e];
        }
        *(h8*)&out_h[(size_t)gr * 128 + c8] = oh;
    }
}

// travel: LDS = aggH(2x64x136 fp16 = 34816B, aliased by hbuf 64x132 fp32 = 33792B) + 2x1024 cols
__global__ __launch_bounds__(256, 3) void travel_mfma(
    const float* xdst, float* out, _Float16* out_h, const _Float16* xdh,
    const _Float16* src1h, const int* rp1, const int* col1, const float* inv1,
    const _Float16* Wl1T, const float* bl1,
    const _Float16* src2h, const int* rp2, const int* col2, const float* inv2,
    const _Float16* Wl2T, const float* bl2,
    const _Float16* WrTh, const float* g, const float* bln) {
    __shared__ __align__(16) char smem[34816 + 8192];
    _Float16* aggH1 = (_Float16*)smem;
    _Float16* aggH2 = (_Float16*)(smem + 17408);
    float* hbuf = (float*)smem;
    int* sC1 = (int*)(smem + 34816);
    int* sC2 = sC1 + 1024;
    sage_mfma_body<1>(blockIdx.x * 64, NT, xdst, out, out_h, xdh,
                      src1h, rp1, col1, inv1, Wl1T, bl1,
                      src2h, rp2, col2, inv2, Wl2T, bl2,
                      WrTh, g, bln, aggH1, aggH2, hbuf, sC1, sC2, 1024);
}

struct UpdParams {
    const float* xdst; float* out; _Float16* out_h;     // out_h == xdh (in-place mirror)
    const _Float16* srch; const int* rp; const int* col; const float* inv;
    const _Float16* WlT; const float* bl; const _Float16* WrT;
    const float* g; const float* bln;
    int nrows;
};

// uv: LDS = hbuf 33792B (aliases aggH 17408B) + 2048 cols
__global__ __launch_bounds__(256, 3) void uv_mfma(UpdParams U, UpdParams V, int nbU) {
    __shared__ __align__(16) char smem[33792 + 8192];
    _Float16* aggH1 = (_Float16*)smem;
    float* hbuf = (float*)smem;
    int* sC1 = (int*)(smem + 33792);
    const bool isU = (int)blockIdx.x < nbU;
    const UpdParams& P = isU ? U : V;
    const int row0 = (isU ? blockIdx.x : blockIdx.x - nbU) * 64;
    sage_mfma_body<0>(row0, P.nrows, P.xdst, P.out, P.out_h, P.out_h,
                      P.srch, P.rp, P.col, P.inv, P.WlT, P.bl,
                      nullptr, nullptr, nullptr, nullptr, nullptr, nullptr,
                      P.WrT, P.g, P.bln, aggH1, nullptr, hbuf, sC1, nullptr, 2048);
}

// ---------------- generic Y[n x 128] = act(LN?(X[n x K]) @ W + b), optional fp16 mirror ----------------

template <int K, bool LN_IN, bool RELU, bool MIRROR>
__global__ __launch_bounds__(256) void gemm_kernel(const float* __restrict__ X,
                                                   const float* __restrict__ W,
                                                   const float* __restrict__ bias,
                                                   float* __restrict__ Y,
                                                   _Float16* __restrict__ Yh,
                                                   const float* __restrict__ g,
                                                   const float* __restrict__ bln) {
    static_assert(!LN_IN || K == 128, "LN input requires K==128");
    __shared__ __align__(16) float As[16 * K];
    const int t = threadIdx.x;
    const size_t row0 = (size_t)blockIdx.x * 16;

    for (int idx = t; idx < 16 * K; idx += 256) As[idx] = X[row0 * K + idx];
    __syncthreads();

    if (LN_IN) {
        const int w = t >> 6, l = t & 63;
        for (int qq = 0; qq < 4; ++qq) {
            const int r = w * 4 + qq;
            float a0 = As[r * K + l], a1 = As[r * K + 64 + l];
            float mm = wave_sum(a0 + a1) * (1.0f / 128.0f);
            float d0 = a0 - mm, d1 = a1 - mm;
            float var = wave_sum(d0 * d0 + d1 * d1) * (1.0f / 128.0f);
            float rs = rsqrtf(var + EPS);
            As[r * K + l] = d0 * rs * g[l] + bln[l];
            As[r * K + 64 + l] = d1 * rs * g[64 + l] + bln[64 + l];
        }
        __syncthreads();
    }

    const int c0 = (t & 31) * 4;
    const int r0 = (t >> 5) * 2;
    v4f b4 = *(const v4f*)&bias[c0];
    v4f acc0 = b4, acc1 = b4;
#pragma unroll 4
    for (int k = 0; k < K; k += 4) {
        v4f a0 = *(const v4f*)&As[r0 * K + k];
        v4f a1 = *(const v4f*)&As[(r0 + 1) * K + k];
        v4f w0 = *(const v4f*)&W[(size_t)(k + 0) * HD + c0];
        v4f w1 = *(const v4f*)&W[(size_t)(k + 1) * HD + c0];
        v4f w2 = *(const v4f*)&W[(size_t)(k + 2) * HD + c0];
        v4f w3 = *(const v4f*)&W[(size_t)(k + 3) * HD + c0];
        acc0 += a0.x * w0 + a0.y * w1 + a0.z * w2 + a0.w * w3;
        acc1 += a1.x * w0 + a1.y * w1 + a1.z * w2 + a1.w * w3;
    }
    if (RELU) {
#pragma unroll
        for (int i = 0; i < 4; ++i) {
            acc0[i] = fmaxf(acc0[i], 0.0f);
            acc1[i] = fmaxf(acc1[i], 0.0f);
        }
    }
    *(v4f*)&Y[(row0 + r0) * HD + c0] = acc0;
    *(v4f*)&Y[(row0 + r0 + 1) * HD + c0] = acc1;
    if (MIRROR) {
        h4 m0, m1;
#pragma unroll
        for (int i = 0; i < 4; ++i) {
            m0[i] = (_Float16)acc0[i];
            m1[i] = (_Float16)acc1[i];
        }
        *(h4*)&Yh[(row0 + r0) * HD + c0] = m0;
        *(h4*)&Yh[(row0 + r0 + 1) * HD + c0] = m1;
    }
}

// ---------------- attention-gate weight folding ----------------

__global__ __launch_bounds__(128) void fold_kernel(const float* __restrict__ Wv,
                                                   const float* __restrict__ bv,
                                                   const float* __restrict__ Wo,
                                                   const float* __restrict__ bo,
                                                   float* __restrict__ Wvo,
                                                   float* __restrict__ bvo) {
    const int c = threadIdx.x;
    const int r = blockIdx.x;
    if (r < 128) {
        float s = 0.f;
        for (int k = 0; k < 128; ++k) s += Wv[r * 128 + k] * Wo[k * 128 + c];
        Wvo[r * 128 + c] = s;
    } else {
        float s = bo[c];
        for (int k = 0; k < 128; ++k) s += bv[k] * Wo[k * 128 + c];
        bvo[c] = s;
    }
}

// ---------------- out[r] = dot(z[r], w2) + b2 ----------------

__global__ __launch_bounds__(256) void dot_kernel(const float* __restrict__ Z,
                                                  const float* __restrict__ w2,
                                                  const float* __restrict__ b2,
                                                  float* __restrict__ out, int n) {
    const int w = threadIdx.x >> 6, l = threadIdx.x & 63;
    const size_t row = (size_t)blockIdx.x * 4 + w;
    if (row < (size_t)n) {
        float v = Z[row * 128 + l] * w2[l] + Z[row * 128 + 64 + l] * w2[64 + l];
        v = wave_sum(v);
        if (l == 0) out[row] = v + b2[0];
    }
}

}  // namespace

extern "C" void kernel_launch(void* const* d_in, const int* in_sizes, int n_in,
                              void* d_out, int out_size, void* d_ws, size_t ws_size,
                              hipStream_t stream) {
    const float* x_user     = (const float*)d_in[0];
    const float* x_travel   = (const float*)d_in[1];
    float*       xv         = (float*)d_in[2];   // updated in place (harness restores inputs)
    const float* W_in_user  = (const float*)d_in[3];
    const float* b_in_user  = (const float*)d_in[4];
    const float* W_in_travel= (const float*)d_in[5];
    const float* b_in_travel= (const float*)d_in[6];
    const float* Wl         = (const float*)d_in[7];
    const float* bl         = (const float*)d_in[8];
    const float* Wr         = (const float*)d_in[9];
    const float* ln_g       = (const float*)d_in[10];
    const float* ln_b       = (const float*)d_in[11];
    // inputs 12..24: expert MLPs (dead) + attn_query/Wq/bq/Wk/bk (dead)
    const float* Wv_        = (const float*)d_in[25];
    const float* bv_        = (const float*)d_in[26];
    const float* Wo_        = (const float*)d_in[27];
    const float* bo_        = (const float*)d_in[28];
    const float* f_ln_g     = (const float*)d_in[29];
    const float* f_ln_b     = (const float*)d_in[30];
    const float* f_W1       = (const float*)d_in[31];
    const float* f_b1       = (const float*)d_in[32];
    const float* f_W2       = (const float*)d_in[33];
    const float* f_b2       = (const float*)d_in[34];
    const int*   ei_ut      = (const int*)d_in[35];
    const int*   ei_tu      = (const int*)d_in[36];
    const int*   ei_tv      = (const int*)d_in[37];
    const int*   ei_vt      = (const int*)d_in[38];
    const int E = in_sizes[35] / 2;

    // ---- workspace layout (~106 MB) ----
    char* wsb = (char*)d_ws;
    size_t off = 0;
    auto alloc = [&](size_t bytes) -> void* {
        off = (off + 511) & ~(size_t)511;
        void* p = wsb + off;
        off += bytes;
        return p;
    };
    float* xu = (float*)alloc((size_t)NU * HD * 4);
    float* xt = (float*)alloc((size_t)NT * HD * 4);
    // fp16 mirrors, padded to 64-row multiples; contiguous region reused as fp32 attn at head
    _Float16* xu_h  = (_Float16*)alloc((size_t)NUP * HD * 2);
    _Float16* xv_h  = (_Float16*)alloc((size_t)NVP * HD * 2);
    _Float16* xt_h0 = (_Float16*)alloc((size_t)NTP * HD * 2);
    _Float16* xt_h1 = (_Float16*)alloc((size_t)NTP * HD * 2);
    _Float16* WT = (_Float16*)alloc((size_t)LAYERS * 7 * 16384 * 2);
    float* Wvo = (float*)alloc(128 * 128 * 4);
    float* bvo = (float*)alloc(128 * 4);

    const int ndst[4] = {NU, NT, NT, NV};  // tu, ut, vt, tv
    int* cur4 = (int*)alloc((size_t)(NU + NT + NT + NV) * 4);
    int *rp[4], *colb[4];
    float* invb[4];
    int* cur[4];
    {
        int coff = 0;
        for (int i = 0; i < 4; ++i) {
            cur[i] = cur4 + coff;
            coff += ndst[i];
            rp[i]   = (int*)alloc((size_t)(ndst[i] + 1) * 4);
            colb[i] = (int*)alloc((size_t)E * 4);
            invb[i] = (float*)alloc((size_t)ndst[i] * 4);
        }
    }

    // ---- batched CSR build ----
    hipMemsetAsync(cur4, 0, (size_t)(NU + NT + NT + NV) * 4, stream);
    CsrJobs J;
    J.j[0] = { ei_tu, ei_tu + E, cur[0], rp[0], colb[0], invb[0], NU };
    J.j[1] = { ei_ut, ei_ut + E, cur[1], rp[1], colb[1], invb[1], NT };
    J.j[2] = { ei_vt, ei_vt + E, cur[2], rp[2], colb[2], invb[2], NT };
    J.j[3] = { ei_tv, ei_tv + E, cur[3], rp[3], colb[3], invb[3], NV };
    const int nbPer = (E + 255) / 256;
    hist_all_kernel<<<4 * nbPer, 256, 0, stream>>>(J, E, nbPer);
    scan4_kernel<<<4, 1024, 0, stream>>>(J);
    scatter_all_kernel<<<4 * nbPer, 256, 0, stream>>>(J, E, nbPer);

    // ---- weight transpose+cast (fp16 W^T) ----
    tw_kernel<<<LAYERS * 7, 256, 0, stream>>>(Wl, Wr, WT);

    // ---- input projections (+ fp16 mirrors) ----
    gemm_kernel<64, false, false, true><<<NU / 16, 256, 0, stream>>>(
        x_user, W_in_user, b_in_user, xu, xu_h, nullptr, nullptr);
    gemm_kernel<32, false, false, true><<<NT / 16, 256, 0, stream>>>(
        x_travel, W_in_travel, b_in_travel, xt, xt_h0, nullptr, nullptr);
    cast_kernel<<<(NV * HD / 4 + 255) / 256, 256, 0, stream>>>(xv, xv_h, NV * HD / 4);

    // ---- 8 hetero-SAGE layers ----
    const int nbU = (NU + 63) / 64;   // 313
    const int nbV = (NV + 63) / 64;   // 1563
    const int nbT = (NT + 63) / 64;   // 782
    for (int i = 0; i < LAYERS; ++i) {
        const _Float16* WTl = WT + (size_t)i * 7 * 16384;
        const float* bl_i = bl + (size_t)i * 4 * 128;
        const float* g_i  = ln_g + (size_t)i * 3 * 128;
        const float* b_i  = ln_b + (size_t)i * 3 * 128;
        _Float16* xth_cur = (i & 1) ? xt_h1 : xt_h0;
        _Float16* xth_nxt = (i & 1) ? xt_h0 : xt_h1;
        // travel: agg(xu_h via ut, Wl0) + agg(xv_h via vt, Wl3) + xt@(Wr0+Wr3);
        // fp32 xt in place (row-local); old xt stays visible via xth_cur mirror.
        travel_mfma<<<nbT, 256, 0, stream>>>(
            xt, xt, xth_nxt, xth_cur,
            xu_h, rp[1], colb[1], invb[1], WTl + 0 * 16384, bl_i + 0 * 128,
            xv_h, rp[2], colb[2], invb[2], WTl + 3 * 16384, bl_i + 3 * 128,
            WTl + 4 * 16384, g_i + 1 * 128, b_i + 1 * 128);
        // user + visit fused: gather OLD xt via xth_cur; in-place row-local
        UpdParams U = { xu, xu, xu_h, xth_cur, rp[0], colb[0], invb[0],
                        WTl + 1 * 16384, bl_i + 1 * 128, WTl + 5 * 16384,
                        g_i + 0 * 128, b_i + 0 * 128, NU };
        UpdParams V = { xv, xv, xv_h, xth_cur, rp[3], colb[3], invb[3],
                        WTl + 2 * 16384, bl_i + 2 * 128, WTl + 6 * 16384,
                        g_i + 2 * 128, b_i + 2 * 128, NV };
        uv_mfma<<<nbU + nbV, 256, 0, stream>>>(U, V, nbU);
    }

    // ---- head ----
    fold_kernel<<<129, 128, 0, stream>>>(Wv_, bv_, Wo_, bo_, Wvo, bvo);
    float* attn = (float*)xu_h;  // mirror region (56.4 MB contiguous) dead at head time
    gemm_kernel<128, false, false, false><<<NV / 16, 256, 0, stream>>>(
        xv, Wvo, bvo, attn, nullptr, nullptr, nullptr);
    gemm_kernel<128, true, true, false><<<NV / 16, 256, 0, stream>>>(
        attn, f_W1, f_b1, attn, nullptr, f_ln_g, f_ln_b);
    dot_kernel<<<NV / 4, 256, 0, stream>>>(attn, f_W2, f_b2, (float*)d_out, NV);
}

// Round 6
// 2440.761 us; speedup vs baseline: 3.1276x; 1.1054x over previous
//
#include <hip/hip_runtime.h>

typedef float v4f __attribute__((ext_vector_type(4)));
typedef _Float16 h4 __attribute__((ext_vector_type(4)));
typedef _Float16 h8 __attribute__((ext_vector_type(8)));

namespace {

constexpr int NU = 20000;
constexpr int NT = 50000;
constexpr int NV = 100000;
constexpr int HD = 128;
constexpr int LAYERS = 8;
constexpr float EPS = 1e-5f;

// padded row counts (multiples of 64) for fp16 mirrors
constexpr int NUP = 20032, NTP = 50048, NVP = 100032;

constexpr int AGS = 136;   // aggH fp16 row stride (16B-aligned: 272B)
constexpr int HBS = 132;   // hbuf fp32 row stride (16B-aligned: 528B, bank-spread)
constexpr int SCB = 2048;  // elements per scan block

__device__ __forceinline__ float wave_sum(float v) {
#pragma unroll
    for (int m = 32; m >= 1; m >>= 1) v += __shfl_xor(v, m, 64);
    return v;
}
__device__ __forceinline__ int wave_sum_i(int v) {
#pragma unroll
    for (int m = 32; m >= 1; m >>= 1) v += __shfl_xor(v, m, 64);
    return v;
}
__device__ __forceinline__ float qsum16(float v) {   // reduce within 16-lane group
#pragma unroll
    for (int m = 8; m >= 1; m >>= 1) v += __shfl_xor(v, m, 64);
    return v;
}

// ---------------- batched CSR build ----------------

struct CsrJob {
    const int* src; const int* dst;
    int* cur; int* rp; int* col; float* inv;
    int n;
};
struct CsrJobs { CsrJob j[4]; };

__global__ void hist_all_kernel(CsrJobs J, int E, int nbPer) {
    const int which = blockIdx.x / nbPer;
    const int e = (blockIdx.x - which * nbPer) * 256 + threadIdx.x;
    if (e < E) atomicAdd(&J.j[which].cur[J.j[which].dst[e]], 1);
}

// hierarchical scan, phase 1: per-block partial sums (64 blocks/job x 2048 elems)
__global__ __launch_bounds__(256) void csr_psum_kernel(CsrJobs J, int* __restrict__ part) {
    const int which = blockIdx.x >> 6;
    const int b = blockIdx.x & 63;
    const CsrJob& job = J.j[which];
    const int n = job.n;
    const int base = b * SCB;
    __shared__ int ws[4];
    int s = 0;
    if (base < n) {
        const int end = min(base + SCB, n);
        for (int i = base + threadIdx.x; i < end; i += 256) s += job.cur[i];
    }
    int sw = wave_sum_i(s);
    if ((threadIdx.x & 63) == 0) ws[threadIdx.x >> 6] = sw;
    __syncthreads();
    if (threadIdx.x == 0) part[which * 64 + b] = ws[0] + ws[1] + ws[2] + ws[3];
}

// phase 2: exclusive scan of the 64 partials per job (one wave per job)
__global__ __launch_bounds__(64) void csr_pscan_kernel(int* __restrict__ part) {
    const int which = blockIdx.x;
    const int t = threadIdx.x;
    int v = part[which * 64 + t];
#pragma unroll
    for (int off = 1; off < 64; off <<= 1) {
        int u = __shfl_up(v, off, 64);
        if (t >= off) v += u;
    }
    int ex = __shfl_up(v, 1, 64);
    if (t == 0) ex = 0;
    part[which * 64 + t] = ex;
}

// phase 3: block-local exclusive scan (8 elems/thread) + offset -> rowptr/inv/cursor
__global__ __launch_bounds__(256) void csr_scan_kernel(CsrJobs J, const int* __restrict__ part) {
    const int which = blockIdx.x >> 6;
    const int b = blockIdx.x & 63;
    const CsrJob& job = J.j[which];
    const int n = job.n;
    const int base = b * SCB;
    if (base >= n) return;
    const int t = threadIdx.x;
    __shared__ int tsum[256];
    int d[8];
    const int i0 = base + t * 8;
    int s = 0;
#pragma unroll
    for (int k = 0; k < 8; ++k) {
        const int i = i0 + k;
        d[k] = (i < n) ? job.cur[i] : 0;
        s += d[k];
    }
    tsum[t] = s;
    __syncthreads();
    for (int off = 1; off < 256; off <<= 1) {
        int u = (t >= off) ? tsum[t - off] : 0;
        __syncthreads();
        tsum[t] += u;
        __syncthreads();
    }
    int run = part[which * 64 + b] + ((t == 0) ? 0 : tsum[t - 1]);
#pragma unroll
    for (int k = 0; k < 8; ++k) {
        const int i = i0 + k;
        if (i < n) {
            job.rp[i] = run;
            job.inv[i] = 1.0f / (float)max(d[k], 1);
            job.cur[i] = run;
            run += d[k];
            if (i == n - 1) job.rp[n] = run;
        }
    }
}

__global__ void scatter_all_kernel(CsrJobs J, int E, int nbPer) {
    const int which = blockIdx.x / nbPer;
    const int e = (blockIdx.x - which * nbPer) * 256 + threadIdx.x;
    if (e < E) {
        const CsrJob& job = J.j[which];
        int p = atomicAdd(&job.cur[job.dst[e]], 1);
        job.col[p] = job.src[e];
    }
}

// ---------------- transpose+cast weights to fp16 W^T ----------------
// slot = layer*7 + j; j=0..3: Wl[layer][j]^T; j=4: (Wr[l][0]+Wr[l][3])^T;
// j=5: Wr[l][1]^T; j=6: Wr[l][2]^T.  WT[slot][n][k] (row-major 128x128 fp16)

__global__ __launch_bounds__(256) void tw_kernel(const float* __restrict__ Wl,
                                                 const float* __restrict__ Wr,
                                                 _Float16* __restrict__ WT) {
    const int slot = blockIdx.x;
    const int layer = slot / 7, j = slot % 7;
    const float* A;
    const float* B = nullptr;
    if (j < 4) A = Wl + ((size_t)layer * 4 + j) * 16384;
    else if (j == 4) {
        A = Wr + ((size_t)layer * 4 + 0) * 16384;
        B = Wr + ((size_t)layer * 4 + 3) * 16384;
    } else A = Wr + ((size_t)layer * 4 + (j - 4)) * 16384;
    _Float16* o = WT + (size_t)slot * 16384;
    for (int idx = threadIdx.x; idx < 16384; idx += 256) {
        const int n = idx >> 7, k = idx & 127;
        float v = A[k * 128 + n];
        if (j == 4) v += B[k * 128 + n];
        o[idx] = (_Float16)v;
    }
}

// ---------------- fp32 -> fp16 cast (xv mirror init) ----------------

__global__ __launch_bounds__(256) void cast_kernel(const float* __restrict__ X,
                                                   _Float16* __restrict__ Y, int n4) {
    int i = blockIdx.x * 256 + threadIdx.x;
    if (i < n4) {
        v4f x = *(const v4f*)(X + (size_t)i * 4);
        h4 y;
        y[0] = (_Float16)x.x; y[1] = (_Float16)x.y;
        y[2] = (_Float16)x.z; y[3] = (_Float16)x.w;
        *(h4*)(Y + (size_t)i * 4) = y;
    }
}

// ---------------- per-row gather into fp16 LDS (MFMA A layout source) ----------------

#define ACC_H8(vh, X, Y)                                                         \
    {                                                                            \
        X.x += (float)vh[0]; X.y += (float)vh[1];                                \
        X.z += (float)vh[2]; X.w += (float)vh[3];                                \
        Y.x += (float)vh[4]; Y.y += (float)vh[5];                                \
        Y.z += (float)vh[6]; Y.w += (float)vh[7];                                \
    }

__device__ __forceinline__ void gather_row_h(
    const _Float16* __restrict__ src, const int* __restrict__ colg,
    const int* __restrict__ sCol, int off_r, int s0, int e1,
    int c8, float iv, _Float16* __restrict__ outRow, int cap) {
    const int d = e1 - s0;
    const int jst = min(d, max(0, cap - off_r));
    v4f aA = {0.f, 0.f, 0.f, 0.f}, aB = aA, bA = aA, bB = aA;
    int j = 0;
    for (; j + 8 <= jst; j += 8) {
        h8 v0 = *(const h8*)(src + (size_t)sCol[off_r + j + 0] * 128 + c8);
        h8 v1 = *(const h8*)(src + (size_t)sCol[off_r + j + 1] * 128 + c8);
        h8 v2 = *(const h8*)(src + (size_t)sCol[off_r + j + 2] * 128 + c8);
        h8 v3 = *(const h8*)(src + (size_t)sCol[off_r + j + 3] * 128 + c8);
        h8 v4 = *(const h8*)(src + (size_t)sCol[off_r + j + 4] * 128 + c8);
        h8 v5 = *(const h8*)(src + (size_t)sCol[off_r + j + 5] * 128 + c8);
        h8 v6 = *(const h8*)(src + (size_t)sCol[off_r + j + 6] * 128 + c8);
        h8 v7 = *(const h8*)(src + (size_t)sCol[off_r + j + 7] * 128 + c8);
        ACC_H8(v0, aA, aB); ACC_H8(v1, bA, bB);
        ACC_H8(v2, aA, aB); ACC_H8(v3, bA, bB);
        ACC_H8(v4, aA, aB); ACC_H8(v5, bA, bB);
        ACC_H8(v6, aA, aB); ACC_H8(v7, bA, bB);
    }
    for (; j < jst; ++j) {
        h8 v0 = *(const h8*)(src + (size_t)sCol[off_r + j] * 128 + c8);
        ACC_H8(v0, aA, aB);
    }
    for (int e = s0 + jst; e < e1; ++e) {   // overflow fallback (rare)
        h8 v0 = *(const h8*)(src + (size_t)colg[e] * 128 + c8);
        ACC_H8(v0, aA, aB);
    }
    v4f r0 = (aA + bA) * iv;
    v4f r1 = (aB + bB) * iv;
    h8 o;
    o[0] = (_Float16)r0.x; o[1] = (_Float16)r0.y; o[2] = (_Float16)r0.z; o[3] = (_Float16)r0.w;
    o[4] = (_Float16)r1.x; o[5] = (_Float16)r1.y; o[6] = (_Float16)r1.z; o[7] = (_Float16)r1.w;
    *(h8*)(outRow + c8) = o;
}

// ---------------- MFMA SAGE update body ----------------
// Block = 256 threads = 4 waves, 64 rows. Wave w owns rows [w*16, w*16+16).
// out = relu(LN(agg1@Wl1 + [agg2@Wl2] + xdst@Wr + bias)) + xdst(fp32)
// A-fragments: agg from LDS fp16; xdst from fp16 mirror (global).
// B-fragments: fp16 W^T from global (L2-hot). Verified layouts:
//   A[m=lane&15][k=quad*8+j], B[k=quad*8+j][n=lane&15], C/D row=quad*4+reg, col=lane&15.

template <int HAS2>
__device__ __forceinline__ void sage_mfma_body(
    int row0, int nrows,
    const float* __restrict__ xdst, float* __restrict__ out,
    _Float16* __restrict__ out_h, const _Float16* __restrict__ xdh,
    const _Float16* __restrict__ src1h, const int* __restrict__ rp1,
    const int* __restrict__ col1, const float* __restrict__ inv1,
    const _Float16* __restrict__ Wl1T, const float* __restrict__ bl1,
    const _Float16* __restrict__ src2h, const int* __restrict__ rp2,
    const int* __restrict__ col2, const float* __restrict__ inv2,
    const _Float16* __restrict__ Wl2T, const float* __restrict__ bl2,
    const _Float16* __restrict__ WrTh,
    const float* __restrict__ g, const float* __restrict__ bln,
    _Float16* aggH1, _Float16* aggH2, float* hbuf, int* sC1, int* sC2, int cap) {
    const int t = threadIdx.x;
    const int w = t >> 6, l = t & 63;
    const int m = l & 15, q = l >> 4;
    const int c8 = m * 8;
    const int rows_end = min(row0 + 64, nrows);

    // stage col indices (block-cooperative)
    const int eb1 = rp1[row0];
    const int cnt1 = min(rp1[rows_end] - eb1, cap);
    for (int i = t; i < cnt1; i += 256) sC1[i] = col1[eb1 + i];
    int eb2 = 0;
    if constexpr (HAS2) {
        eb2 = rp2[row0];
        const int cnt2 = min(rp2[rows_end] - eb2, cap);
        for (int i = t; i < cnt2; i += 256) sC2[i] = col2[eb2 + i];
    }
    __syncthreads();

    // Phase A: gather (quarter-wave per row, 4 rows each)
#pragma unroll
    for (int i = 0; i < 4; ++i) {
        const int rloc = w * 16 + q * 4 + i;
        const int gr = row0 + rloc;
        if (gr < nrows) {
            {
                const int s0 = rp1[gr], e1r = rp1[gr + 1];
                gather_row_h(src1h, col1, sC1, s0 - eb1, s0, e1r, c8, inv1[gr],
                             aggH1 + (size_t)rloc * AGS, cap);
            }
            if constexpr (HAS2) {
                const int s0 = rp2[gr], e1r = rp2[gr + 1];
                gather_row_h(src2h, col2, sC2, s0 - eb2, s0, e1r, c8, inv2[gr],
                             aggH2 + (size_t)rloc * AGS, cap);
            }
        }
    }

    // Phase B: MFMA. acc[nt] covers cols [nt*16, nt*16+16), rows w*16+q*4+reg.
    v4f acc[8];
#pragma unroll
    for (int nt = 0; nt < 8; ++nt) acc[nt] = (v4f){0.f, 0.f, 0.f, 0.f};

    // xdst term (fp16 mirror, no LDS dependency)
    const _Float16* xdrow = xdh + (size_t)(row0 + w * 16 + m) * 128;
#pragma unroll
    for (int kt = 0; kt < 4; ++kt) {
        h8 a = *(const h8*)(xdrow + kt * 32 + q * 8);
#pragma unroll
        for (int nt = 0; nt < 8; ++nt) {
            h8 b = *(const h8*)(WrTh + (size_t)(nt * 16 + m) * 128 + kt * 32 + q * 8);
            acc[nt] = __builtin_amdgcn_mfma_f32_16x16x32_f16(a, b, acc[nt], 0, 0, 0);
        }
    }
    __syncthreads();   // aggH writes visible / ordered

    const _Float16* arow1 = aggH1 + (size_t)(w * 16 + m) * AGS;
#pragma unroll
    for (int kt = 0; kt < 4; ++kt) {
        h8 a = *(const h8*)(arow1 + kt * 32 + q * 8);
#pragma unroll
        for (int nt = 0; nt < 8; ++nt) {
            h8 b = *(const h8*)(Wl1T + (size_t)(nt * 16 + m) * 128 + kt * 32 + q * 8);
            acc[nt] = __builtin_amdgcn_mfma_f32_16x16x32_f16(a, b, acc[nt], 0, 0, 0);
        }
    }
    if constexpr (HAS2) {
        const _Float16* arow2 = aggH2 + (size_t)(w * 16 + m) * AGS;
#pragma unroll
        for (int kt = 0; kt < 4; ++kt) {
            h8 a = *(const h8*)(arow2 + kt * 32 + q * 8);
#pragma unroll
            for (int nt = 0; nt < 8; ++nt) {
                h8 b = *(const h8*)(Wl2T + (size_t)(nt * 16 + m) * 128 + kt * 32 + q * 8);
                acc[nt] = __builtin_amdgcn_mfma_f32_16x16x32_f16(a, b, acc[nt], 0, 0, 0);
            }
        }
    }
    __syncthreads();   // all agg reads done before hbuf (aliased) overwrites

    // acc -> hbuf (layout transform for coalesced epilogue)
#pragma unroll
    for (int nt = 0; nt < 8; ++nt)
#pragma unroll
        for (int r = 0; r < 4; ++r)
            hbuf[(size_t)(w * 16 + q * 4 + r) * HBS + nt * 16 + m] = acc[nt][r];
    __syncthreads();

    // Phase C: bias + LayerNorm + ReLU + fp32 residual; fp32 + fp16 mirror stores
    v4f bg0 = *(const v4f*)&bl1[c8];
    v4f bg1 = *(const v4f*)&bl1[c8 + 4];
    if constexpr (HAS2) {
        bg0 += *(const v4f*)&bl2[c8];
        bg1 += *(const v4f*)&bl2[c8 + 4];
    }
    v4f g0 = *(const v4f*)&g[c8], g1 = *(const v4f*)&g[c8 + 4];
    v4f lb0 = *(const v4f*)&bln[c8], lb1 = *(const v4f*)&bln[c8 + 4];
#pragma unroll
    for (int i = 0; i < 4; ++i) {
        const int rloc = w * 16 + q * 4 + i;
        const int gr = row0 + rloc;
        if (gr >= nrows) continue;
        v4f h0 = *(const v4f*)&hbuf[(size_t)rloc * HBS + c8] + bg0;
        v4f h1 = *(const v4f*)&hbuf[(size_t)rloc * HBS + c8 + 4] + bg1;
        float part = h0.x + h0.y + h0.z + h0.w + h1.x + h1.y + h1.z + h1.w;
        float mean = qsum16(part) * (1.0f / 128.0f);
        v4f d0 = h0 - mean, d1 = h1 - mean;
        float vp = d0.x * d0.x + d0.y * d0.y + d0.z * d0.z + d0.w * d0.w +
                   d1.x * d1.x + d1.y * d1.y + d1.z * d1.z + d1.w * d1.w;
        float var = qsum16(vp) * (1.0f / 128.0f);
        float rs = rsqrtf(var + EPS);
        v4f x0 = *(const v4f*)&xdst[(size_t)gr * 128 + c8];
        v4f x1 = *(const v4f*)&xdst[(size_t)gr * 128 + c8 + 4];
        v4f y0, y1;
#pragma unroll
        for (int e = 0; e < 4; ++e) {
            y0[e] = fmaxf(d0[e] * rs * g0[e] + lb0[e], 0.f) + x0[e];
            y1[e] = fmaxf(d1[e] * rs * g1[e] + lb1[e], 0.f) + x1[e];
        }
        *(v4f*)&out[(size_t)gr * 128 + c8] = y0;
        *(v4f*)&out[(size_t)gr * 128 + c8 + 4] = y1;
        h8 oh;
#pragma unroll
        for (int e = 0; e < 4; ++e) {
            oh[e] = (_Float16)y0[e];
            oh[4 + e] = (_Float16)y1[e];
        }
        *(h8*)&out_h[(size_t)gr * 128 + c8] = oh;
    }
}

// travel: LDS = aggH(2x64x136 fp16 = 34816B, aliased by hbuf 64x132 fp32 = 33792B) + 2x1024 cols
__global__ __launch_bounds__(256, 3) void travel_mfma(
    const float* xdst, float* out, _Float16* out_h, const _Float16* xdh,
    const _Float16* src1h, const int* rp1, const int* col1, const float* inv1,
    const _Float16* Wl1T, const float* bl1,
    const _Float16* src2h, const int* rp2, const int* col2, const float* inv2,
    const _Float16* Wl2T, const float* bl2,
    const _Float16* WrTh, const float* g, const float* bln) {
    __shared__ __align__(16) char smem[34816 + 8192];
    _Float16* aggH1 = (_Float16*)smem;
    _Float16* aggH2 = (_Float16*)(smem + 17408);
    float* hbuf = (float*)smem;
    int* sC1 = (int*)(smem + 34816);
    int* sC2 = sC1 + 1024;
    sage_mfma_body<1>(blockIdx.x * 64, NT, xdst, out, out_h, xdh,
                      src1h, rp1, col1, inv1, Wl1T, bl1,
                      src2h, rp2, col2, inv2, Wl2T, bl2,
                      WrTh, g, bln, aggH1, aggH2, hbuf, sC1, sC2, 1024);
}

struct UpdParams {
    const float* xdst; float* out; _Float16* out_h;     // out_h == xdh (in-place mirror)
    const _Float16* srch; const int* rp; const int* col; const float* inv;
    const _Float16* WlT; const float* bl; const _Float16* WrT;
    const float* g; const float* bln;
    int nrows;
};

// uv: LDS = hbuf 33792B (aliases aggH 17408B) + 2048 cols
__global__ __launch_bounds__(256, 3) void uv_mfma(UpdParams U, UpdParams V, int nbU) {
    __shared__ __align__(16) char smem[33792 + 8192];
    _Float16* aggH1 = (_Float16*)smem;
    float* hbuf = (float*)smem;
    int* sC1 = (int*)(smem + 33792);
    const bool isU = (int)blockIdx.x < nbU;
    const UpdParams& P = isU ? U : V;
    const int row0 = (isU ? blockIdx.x : blockIdx.x - nbU) * 64;
    sage_mfma_body<0>(row0, P.nrows, P.xdst, P.out, P.out_h, P.out_h,
                      P.srch, P.rp, P.col, P.inv, P.WlT, P.bl,
                      nullptr, nullptr, nullptr, nullptr, nullptr, nullptr,
                      P.WrT, P.g, P.bln, aggH1, nullptr, hbuf, sC1, nullptr, 2048);
}

// ---------------- generic Y[n x 128] = act(LN?(X[n x K]) @ W + b), optional fp16 mirror ----------------

template <int K, bool LN_IN, bool RELU, bool MIRROR>
__global__ __launch_bounds__(256) void gemm_kernel(const float* __restrict__ X,
                                                   const float* __restrict__ W,
                                                   const float* __restrict__ bias,
                                                   float* __restrict__ Y,
                                                   _Float16* __restrict__ Yh,
                                                   const float* __restrict__ g,
                                                   const float* __restrict__ bln) {
    static_assert(!LN_IN || K == 128, "LN input requires K==128");
    __shared__ __align__(16) float As[16 * K];
    const int t = threadIdx.x;
    const size_t row0 = (size_t)blockIdx.x * 16;

    for (int idx = t; idx < 16 * K; idx += 256) As[idx] = X[row0 * K + idx];
    __syncthreads();

    if (LN_IN) {
        const int w = t >> 6, l = t & 63;
        for (int qq = 0; qq < 4; ++qq) {
            const int r = w * 4 + qq;
            float a0 = As[r * K + l], a1 = As[r * K + 64 + l];
            float mm = wave_sum(a0 + a1) * (1.0f / 128.0f);
            float d0 = a0 - mm, d1 = a1 - mm;
            float var = wave_sum(d0 * d0 + d1 * d1) * (1.0f / 128.0f);
            float rs = rsqrtf(var + EPS);
            As[r * K + l] = d0 * rs * g[l] + bln[l];
            As[r * K + 64 + l] = d1 * rs * g[64 + l] + bln[64 + l];
        }
        __syncthreads();
    }

    const int c0 = (t & 31) * 4;
    const int r0 = (t >> 5) * 2;
    v4f b4 = *(const v4f*)&bias[c0];
    v4f acc0 = b4, acc1 = b4;
#pragma unroll 4
    for (int k = 0; k < K; k += 4) {
        v4f a0 = *(const v4f*)&As[r0 * K + k];
        v4f a1 = *(const v4f*)&As[(r0 + 1) * K + k];
        v4f w0 = *(const v4f*)&W[(size_t)(k + 0) * HD + c0];
        v4f w1 = *(const v4f*)&W[(size_t)(k + 1) * HD + c0];
        v4f w2 = *(const v4f*)&W[(size_t)(k + 2) * HD + c0];
        v4f w3 = *(const v4f*)&W[(size_t)(k + 3) * HD + c0];
        acc0 += a0.x * w0 + a0.y * w1 + a0.z * w2 + a0.w * w3;
        acc1 += a1.x * w0 + a1.y * w1 + a1.z * w2 + a1.w * w3;
    }
    if (RELU) {
#pragma unroll
        for (int i = 0; i < 4; ++i) {
            acc0[i] = fmaxf(acc0[i], 0.0f);
            acc1[i] = fmaxf(acc1[i], 0.0f);
        }
    }
    *(v4f*)&Y[(row0 + r0) * HD + c0] = acc0;
    *(v4f*)&Y[(row0 + r0 + 1) * HD + c0] = acc1;
    if (MIRROR) {
        h4 m0, m1;
#pragma unroll
        for (int i = 0; i < 4; ++i) {
            m0[i] = (_Float16)acc0[i];
            m1[i] = (_Float16)acc1[i];
        }
        *(h4*)&Yh[(row0 + r0) * HD + c0] = m0;
        *(h4*)&Yh[(row0 + r0 + 1) * HD + c0] = m1;
    }
}

// ---------------- attention-gate weight folding ----------------

__global__ __launch_bounds__(128) void fold_kernel(const float* __restrict__ Wv,
                                                   const float* __restrict__ bv,
                                                   const float* __restrict__ Wo,
                                                   const float* __restrict__ bo,
                                                   float* __restrict__ Wvo,
                                                   float* __restrict__ bvo) {
    const int c = threadIdx.x;
    const int r = blockIdx.x;
    if (r < 128) {
        float s = 0.f;
        for (int k = 0; k < 128; ++k) s += Wv[r * 128 + k] * Wo[k * 128 + c];
        Wvo[r * 128 + c] = s;
    } else {
        float s = bo[c];
        for (int k = 0; k < 128; ++k) s += bv[k] * Wo[k * 128 + c];
        bvo[c] = s;
    }
}

// ---------------- out[r] = dot(z[r], w2) + b2 ----------------

__global__ __launch_bounds__(256) void dot_kernel(const float* __restrict__ Z,
                                                  const float* __restrict__ w2,
                                                  const float* __restrict__ b2,
                                                  float* __restrict__ out, int n) {
    const int w = threadIdx.x >> 6, l = threadIdx.x & 63;
    const size_t row = (size_t)blockIdx.x * 4 + w;
    if (row < (size_t)n) {
        float v = Z[row * 128 + l] * w2[l] + Z[row * 128 + 64 + l] * w2[64 + l];
        v = wave_sum(v);
        if (l == 0) out[row] = v + b2[0];
    }
}

}  // namespace

extern "C" void kernel_launch(void* const* d_in, const int* in_sizes, int n_in,
                              void* d_out, int out_size, void* d_ws, size_t ws_size,
                              hipStream_t stream) {
    const float* x_user     = (const float*)d_in[0];
    const float* x_travel   = (const float*)d_in[1];
    float*       xv         = (float*)d_in[2];   // updated in place (harness restores inputs)
    const float* W_in_user  = (const float*)d_in[3];
    const float* b_in_user  = (const float*)d_in[4];
    const float* W_in_travel= (const float*)d_in[5];
    const float* b_in_travel= (const float*)d_in[6];
    const float* Wl         = (const float*)d_in[7];
    const float* bl         = (const float*)d_in[8];
    const float* Wr         = (const float*)d_in[9];
    const float* ln_g       = (const float*)d_in[10];
    const float* ln_b       = (const float*)d_in[11];
    // inputs 12..24: expert MLPs (dead) + attn_query/Wq/bq/Wk/bk (dead)
    const float* Wv_        = (const float*)d_in[25];
    const float* bv_        = (const float*)d_in[26];
    const float* Wo_        = (const float*)d_in[27];
    const float* bo_        = (const float*)d_in[28];
    const float* f_ln_g     = (const float*)d_in[29];
    const float* f_ln_b     = (const float*)d_in[30];
    const float* f_W1       = (const float*)d_in[31];
    const float* f_b1       = (const float*)d_in[32];
    const float* f_W2       = (const float*)d_in[33];
    const float* f_b2       = (const float*)d_in[34];
    const int*   ei_ut      = (const int*)d_in[35];
    const int*   ei_tu      = (const int*)d_in[36];
    const int*   ei_tv      = (const int*)d_in[37];
    const int*   ei_vt      = (const int*)d_in[38];
    const int E = in_sizes[35] / 2;

    // ---- workspace layout (~106 MB) ----
    char* wsb = (char*)d_ws;
    size_t off = 0;
    auto alloc = [&](size_t bytes) -> void* {
        off = (off + 511) & ~(size_t)511;
        void* p = wsb + off;
        off += bytes;
        return p;
    };
    float* xu = (float*)alloc((size_t)NU * HD * 4);
    float* xt = (float*)alloc((size_t)NT * HD * 4);
    // fp16 mirrors, padded to 64-row multiples; contiguous region reused as fp32 attn at head
    _Float16* xu_h  = (_Float16*)alloc((size_t)NUP * HD * 2);
    _Float16* xv_h  = (_Float16*)alloc((size_t)NVP * HD * 2);
    _Float16* xt_h0 = (_Float16*)alloc((size_t)NTP * HD * 2);
    _Float16* xt_h1 = (_Float16*)alloc((size_t)NTP * HD * 2);
    _Float16* WT = (_Float16*)alloc((size_t)LAYERS * 7 * 16384 * 2);
    float* Wvo = (float*)alloc(128 * 128 * 4);
    float* bvo = (float*)alloc(128 * 4);
    int* part = (int*)alloc(4 * 64 * 4);

    const int ndst[4] = {NU, NT, NT, NV};  // tu, ut, vt, tv
    int* cur4 = (int*)alloc((size_t)(NU + NT + NT + NV) * 4);
    int *rp[4], *colb[4];
    float* invb[4];
    int* cur[4];
    {
        int coff = 0;
        for (int i = 0; i < 4; ++i) {
            cur[i] = cur4 + coff;
            coff += ndst[i];
            rp[i]   = (int*)alloc((size_t)(ndst[i] + 1) * 4);
            colb[i] = (int*)alloc((size_t)E * 4);
            invb[i] = (float*)alloc((size_t)ndst[i] * 4);
        }
    }

    // ---- batched CSR build (hierarchical scan) ----
    hipMemsetAsync(cur4, 0, (size_t)(NU + NT + NT + NV) * 4, stream);
    CsrJobs J;
    J.j[0] = { ei_tu, ei_tu + E, cur[0], rp[0], colb[0], invb[0], NU };
    J.j[1] = { ei_ut, ei_ut + E, cur[1], rp[1], colb[1], invb[1], NT };
    J.j[2] = { ei_vt, ei_vt + E, cur[2], rp[2], colb[2], invb[2], NT };
    J.j[3] = { ei_tv, ei_tv + E, cur[3], rp[3], colb[3], invb[3], NV };
    const int nbPer = (E + 255) / 256;
    hist_all_kernel<<<4 * nbPer, 256, 0, stream>>>(J, E, nbPer);
    csr_psum_kernel<<<4 * 64, 256, 0, stream>>>(J, part);
    csr_pscan_kernel<<<4, 64, 0, stream>>>(part);
    csr_scan_kernel<<<4 * 64, 256, 0, stream>>>(J, part);
    scatter_all_kernel<<<4 * nbPer, 256, 0, stream>>>(J, E, nbPer);

    // ---- weight transpose+cast (fp16 W^T) ----
    tw_kernel<<<LAYERS * 7, 256, 0, stream>>>(Wl, Wr, WT);

    // ---- input projections (+ fp16 mirrors) ----
    gemm_kernel<64, false, false, true><<<NU / 16, 256, 0, stream>>>(
        x_user, W_in_user, b_in_user, xu, xu_h, nullptr, nullptr);
    gemm_kernel<32, false, false, true><<<NT / 16, 256, 0, stream>>>(
        x_travel, W_in_travel, b_in_travel, xt, xt_h0, nullptr, nullptr);
    cast_kernel<<<(NV * HD / 4 + 255) / 256, 256, 0, stream>>>(xv, xv_h, NV * HD / 4);

    // ---- 8 hetero-SAGE layers ----
    const int nbU = (NU + 63) / 64;   // 313
    const int nbV = (NV + 63) / 64;   // 1563
    const int nbT = (NT + 63) / 64;   // 782
    for (int i = 0; i < LAYERS; ++i) {
        const _Float16* WTl = WT + (size_t)i * 7 * 16384;
        const float* bl_i = bl + (size_t)i * 4 * 128;
        const float* g_i  = ln_g + (size_t)i * 3 * 128;
        const float* b_i  = ln_b + (size_t)i * 3 * 128;
        _Float16* xth_cur = (i & 1) ? xt_h1 : xt_h0;
        _Float16* xth_nxt = (i & 1) ? xt_h0 : xt_h1;
        // travel: agg(xu_h via ut, Wl0) + agg(xv_h via vt, Wl3) + xt@(Wr0+Wr3);
        // fp32 xt in place (row-local); old xt stays visible via xth_cur mirror.
        travel_mfma<<<nbT, 256, 0, stream>>>(
            xt, xt, xth_nxt, xth_cur,
            xu_h, rp[1], colb[1], invb[1], WTl + 0 * 16384, bl_i + 0 * 128,
            xv_h, rp[2], colb[2], invb[2], WTl + 3 * 16384, bl_i + 3 * 128,
            WTl + 4 * 16384, g_i + 1 * 128, b_i + 1 * 128);
        // user + visit fused: gather OLD xt via xth_cur; in-place row-local
        UpdParams U = { xu, xu, xu_h, xth_cur, rp[0], colb[0], invb[0],
                        WTl + 1 * 16384, bl_i + 1 * 128, WTl + 5 * 16384,
                        g_i + 0 * 128, b_i + 0 * 128, NU };
        UpdParams V = { xv, xv, xv_h, xth_cur, rp[3], colb[3], invb[3],
                        WTl + 2 * 16384, bl_i + 2 * 128, WTl + 6 * 16384,
                        g_i + 2 * 128, b_i + 2 * 128, NV };
        uv_mfma<<<nbU + nbV, 256, 0, stream>>>(U, V, nbU);
    }

    // ---- head ----
    fold_kernel<<<129, 128, 0, stream>>>(Wv_, bv_, Wo_, bo_, Wvo, bvo);
    float* attn = (float*)xu_h;  // mirror region (56.4 MB contiguous) dead at head time
    gemm_kernel<128, false, false, false><<<NV / 16, 256, 0, stream>>>(
        xv, Wvo, bvo, attn, nullptr, nullptr, nullptr);
    gemm_kernel<128, true, true, false><<<NV / 16, 256, 0, stream>>>(
        attn, f_W1, f_b1, attn, nullptr, f_ln_g, f_ln_b);
    dot_kernel<<<NV / 4, 256, 0, stream>>>(attn, f_W2, f_b2, (float*)d_out, NV);
}

// Round 7
// 2166.446 us; speedup vs baseline: 3.5237x; 1.1266x over previous
//
#include <hip/hip_runtime.h>

typedef float v4f __attribute__((ext_vector_type(4)));
typedef _Float16 h4 __attribute__((ext_vector_type(4)));
typedef _Float16 h8 __attribute__((ext_vector_type(8)));

namespace {

constexpr int NU = 20000;
constexpr int NT = 50000;
constexpr int NV = 100000;
constexpr int HD = 128;
constexpr int LAYERS = 8;
constexpr float EPS = 1e-5f;

// padded row counts (multiples of 64) for fp16 mirrors
constexpr int NUP = 20032, NTP = 50048, NVP = 100032;

constexpr int AGS = 136;   // aggH fp16 row stride (16B-aligned: 272B)
constexpr int HBS = 132;   // hbuf fp32 row stride (16B-aligned: 528B, bank-spread)
constexpr int SCB = 2048;  // elements per scan block
constexpr int ECH = 2048;  // edges per hist/scatter block chunk

__device__ __forceinline__ float wave_sum(float v) {
#pragma unroll
    for (int m = 32; m >= 1; m >>= 1) v += __shfl_xor(v, m, 64);
    return v;
}
__device__ __forceinline__ int wave_sum_i(int v) {
#pragma unroll
    for (int m = 32; m >= 1; m >>= 1) v += __shfl_xor(v, m, 64);
    return v;
}
__device__ __forceinline__ float qsum16(float v) {   // reduce within 16-lane group
#pragma unroll
    for (int m = 8; m >= 1; m >>= 1) v += __shfl_xor(v, m, 64);
    return v;
}

// ---------------- batched CSR build ----------------

struct CsrJob {
    const int* src; const int* dst;
    int* cur; int* rp; int* col; float* inv;
    int n;
};
struct CsrJobs { CsrJob j[4]; };

// XCD-residue partitioning: block with residue r (blockIdx%8, the likely XCD id)
// only touches dst in [r*n/8, (r+1)*n/8) -> cursor atomics + col writes stay in
// one XCD's L2, full lines assemble before eviction (kills partial-line HBM
// write amplification). Correct regardless of the actual block->XCD mapping.

__global__ __launch_bounds__(256) void hist_all_kernel(CsrJobs J, int E, int nbPer) {
    const int r = blockIdx.x & 7;
    const int rest = blockIdx.x >> 3;
    const int which = rest / nbPer;
    const int chunk = rest - which * nbPer;
    const CsrJob& job = J.j[which];
    const int n = job.n;
    const int lo = r * (n >> 3);
    const int hi = (r == 7) ? n : lo + (n >> 3);
    const int base = chunk * ECH;
    const int end = min(base + ECH, E);
    for (int e = base + threadIdx.x; e < end; e += 256) {
        const int d = job.dst[e];
        if (d >= lo && d < hi) atomicAdd(&job.cur[d], 1);
    }
}

// hierarchical scan, phase 1: per-block partial sums (64 blocks/job x 2048 elems)
__global__ __launch_bounds__(256) void csr_psum_kernel(CsrJobs J, int* __restrict__ part) {
    const int which = blockIdx.x >> 6;
    const int b = blockIdx.x & 63;
    const CsrJob& job = J.j[which];
    const int n = job.n;
    const int base = b * SCB;
    __shared__ int ws[4];
    int s = 0;
    if (base < n) {
        const int end = min(base + SCB, n);
        for (int i = base + threadIdx.x; i < end; i += 256) s += job.cur[i];
    }
    int sw = wave_sum_i(s);
    if ((threadIdx.x & 63) == 0) ws[threadIdx.x >> 6] = sw;
    __syncthreads();
    if (threadIdx.x == 0) part[which * 64 + b] = ws[0] + ws[1] + ws[2] + ws[3];
}

// phase 2: exclusive scan of the 64 partials per job (one wave per job)
__global__ __launch_bounds__(64) void csr_pscan_kernel(int* __restrict__ part) {
    const int which = blockIdx.x;
    const int t = threadIdx.x;
    int v = part[which * 64 + t];
#pragma unroll
    for (int off = 1; off < 64; off <<= 1) {
        int u = __shfl_up(v, off, 64);
        if (t >= off) v += u;
    }
    int ex = __shfl_up(v, 1, 64);
    if (t == 0) ex = 0;
    part[which * 64 + t] = ex;
}

// phase 3: block-local exclusive scan (8 elems/thread) + offset -> rowptr/inv/cursor
__global__ __launch_bounds__(256) void csr_scan_kernel(CsrJobs J, const int* __restrict__ part) {
    const int which = blockIdx.x >> 6;
    const int b = blockIdx.x & 63;
    const CsrJob& job = J.j[which];
    const int n = job.n;
    const int base = b * SCB;
    if (base >= n) return;
    const int t = threadIdx.x;
    __shared__ int tsum[256];
    int d[8];
    const int i0 = base + t * 8;
    int s = 0;
#pragma unroll
    for (int k = 0; k < 8; ++k) {
        const int i = i0 + k;
        d[k] = (i < n) ? job.cur[i] : 0;
        s += d[k];
    }
    tsum[t] = s;
    __syncthreads();
    for (int off = 1; off < 256; off <<= 1) {
        int u = (t >= off) ? tsum[t - off] : 0;
        __syncthreads();
        tsum[t] += u;
        __syncthreads();
    }
    int run = part[which * 64 + b] + ((t == 0) ? 0 : tsum[t - 1]);
#pragma unroll
    for (int k = 0; k < 8; ++k) {
        const int i = i0 + k;
        if (i < n) {
            job.rp[i] = run;
            job.inv[i] = 1.0f / (float)max(d[k], 1);
            job.cur[i] = run;
            run += d[k];
            if (i == n - 1) job.rp[n] = run;
        }
    }
}

__global__ __launch_bounds__(256) void scatter_all_kernel(CsrJobs J, int E, int nbPer) {
    const int r = blockIdx.x & 7;
    const int rest = blockIdx.x >> 3;
    const int which = rest / nbPer;
    const int chunk = rest - which * nbPer;
    const CsrJob& job = J.j[which];
    const int n = job.n;
    const int lo = r * (n >> 3);
    const int hi = (r == 7) ? n : lo + (n >> 3);
    const int base = chunk * ECH;
    const int end = min(base + ECH, E);
    for (int e = base + threadIdx.x; e < end; e += 256) {
        const int d = job.dst[e];
        if (d >= lo && d < hi) {
            int p = atomicAdd(&job.cur[d], 1);
            job.col[p] = job.src[e];
        }
    }
}

// ---------------- transpose+cast weights to fp16 W^T ----------------
// slot = layer*7 + j; j=0..3: Wl[layer][j]^T; j=4: (Wr[l][0]+Wr[l][3])^T;
// j=5: Wr[l][1]^T; j=6: Wr[l][2]^T.  WT[slot][n][k] (row-major 128x128 fp16)

__global__ __launch_bounds__(256) void tw_kernel(const float* __restrict__ Wl,
                                                 const float* __restrict__ Wr,
                                                 _Float16* __restrict__ WT) {
    const int slot = blockIdx.x;
    const int layer = slot / 7, j = slot % 7;
    const float* A;
    const float* B = nullptr;
    if (j < 4) A = Wl + ((size_t)layer * 4 + j) * 16384;
    else if (j == 4) {
        A = Wr + ((size_t)layer * 4 + 0) * 16384;
        B = Wr + ((size_t)layer * 4 + 3) * 16384;
    } else A = Wr + ((size_t)layer * 4 + (j - 4)) * 16384;
    _Float16* o = WT + (size_t)slot * 16384;
    for (int idx = threadIdx.x; idx < 16384; idx += 256) {
        const int n = idx >> 7, k = idx & 127;
        float v = A[k * 128 + n];
        if (j == 4) v += B[k * 128 + n];
        o[idx] = (_Float16)v;
    }
}

// ---------------- fp32 -> fp16 cast (xv mirror init) ----------------

__global__ __launch_bounds__(256) void cast_kernel(const float* __restrict__ X,
                                                   _Float16* __restrict__ Y, int n4) {
    int i = blockIdx.x * 256 + threadIdx.x;
    if (i < n4) {
        v4f x = *(const v4f*)(X + (size_t)i * 4);
        h4 y;
        y[0] = (_Float16)x.x; y[1] = (_Float16)x.y;
        y[2] = (_Float16)x.z; y[3] = (_Float16)x.w;
        *(h4*)(Y + (size_t)i * 4) = y;
    }
}

// ---------------- per-row gather into fp16 LDS (MFMA A layout source) ----------------

#define ACC_H8(vh, X, Y)                                                         \
    {                                                                            \
        X.x += (float)vh[0]; X.y += (float)vh[1];                                \
        X.z += (float)vh[2]; X.w += (float)vh[3];                                \
        Y.x += (float)vh[4]; Y.y += (float)vh[5];                                \
        Y.z += (float)vh[6]; Y.w += (float)vh[7];                                \
    }

__device__ __forceinline__ void gather_row_h(
    const _Float16* __restrict__ src, const int* __restrict__ colg,
    const int* __restrict__ sCol, int off_r, int s0, int e1,
    int c8, float iv, _Float16* __restrict__ outRow, int cap) {
    const int d = e1 - s0;
    const int jst = min(d, max(0, cap - off_r));
    v4f aA = {0.f, 0.f, 0.f, 0.f}, aB = aA, bA = aA, bB = aA;
    int j = 0;
    for (; j + 8 <= jst; j += 8) {
        h8 v0 = *(const h8*)(src + (size_t)sCol[off_r + j + 0] * 128 + c8);
        h8 v1 = *(const h8*)(src + (size_t)sCol[off_r + j + 1] * 128 + c8);
        h8 v2 = *(const h8*)(src + (size_t)sCol[off_r + j + 2] * 128 + c8);
        h8 v3 = *(const h8*)(src + (size_t)sCol[off_r + j + 3] * 128 + c8);
        h8 v4 = *(const h8*)(src + (size_t)sCol[off_r + j + 4] * 128 + c8);
        h8 v5 = *(const h8*)(src + (size_t)sCol[off_r + j + 5] * 128 + c8);
        h8 v6 = *(const h8*)(src + (size_t)sCol[off_r + j + 6] * 128 + c8);
        h8 v7 = *(const h8*)(src + (size_t)sCol[off_r + j + 7] * 128 + c8);
        ACC_H8(v0, aA, aB); ACC_H8(v1, bA, bB);
        ACC_H8(v2, aA, aB); ACC_H8(v3, bA, bB);
        ACC_H8(v4, aA, aB); ACC_H8(v5, bA, bB);
        ACC_H8(v6, aA, aB); ACC_H8(v7, bA, bB);
    }
    for (; j < jst; ++j) {
        h8 v0 = *(const h8*)(src + (size_t)sCol[off_r + j] * 128 + c8);
        ACC_H8(v0, aA, aB);
    }
    for (int e = s0 + jst; e < e1; ++e) {   // overflow fallback (rare)
        h8 v0 = *(const h8*)(src + (size_t)colg[e] * 128 + c8);
        ACC_H8(v0, aA, aB);
    }
    v4f r0 = (aA + bA) * iv;
    v4f r1 = (aB + bB) * iv;
    h8 o;
    o[0] = (_Float16)r0.x; o[1] = (_Float16)r0.y; o[2] = (_Float16)r0.z; o[3] = (_Float16)r0.w;
    o[4] = (_Float16)r1.x; o[5] = (_Float16)r1.y; o[6] = (_Float16)r1.z; o[7] = (_Float16)r1.w;
    *(h8*)(outRow + c8) = o;
}

// ---------------- MFMA SAGE update body ----------------
// Block = 256 threads = 4 waves, 64 rows. Wave w owns rows [w*16, w*16+16).
// out = relu(LN(agg1@Wl1 + [agg2@Wl2] + xdst@Wr + bias)) + xdst(fp32)
// A-fragments: agg from LDS fp16; xdst term from fp16 mirror xdh (global).
// B-fragments: fp16 W^T from global (L2-hot). Verified layouts:
//   A[m=lane&15][k=quad*8+j], B[k=quad*8+j][n=lane&15], C/D row=quad*4+reg, col=lane&15.

template <int HAS2>
__device__ __forceinline__ void sage_mfma_body(
    int row0, int nrows,
    const float* __restrict__ xdst, float* __restrict__ out,
    _Float16* __restrict__ out_h, const _Float16* __restrict__ xdh,
    const _Float16* __restrict__ src1h, const int* __restrict__ rp1,
    const int* __restrict__ col1, const float* __restrict__ inv1,
    const _Float16* __restrict__ Wl1T, const float* __restrict__ bl1,
    const _Float16* __restrict__ src2h, const int* __restrict__ rp2,
    const int* __restrict__ col2, const float* __restrict__ inv2,
    const _Float16* __restrict__ Wl2T, const float* __restrict__ bl2,
    const _Float16* __restrict__ WrTh,
    const float* __restrict__ g, const float* __restrict__ bln,
    _Float16* aggH1, _Float16* aggH2, float* hbuf, int* sC1, int* sC2, int cap) {
    const int t = threadIdx.x;
    const int w = t >> 6, l = t & 63;
    const int m = l & 15, q = l >> 4;
    const int c8 = m * 8;
    const int rows_end = min(row0 + 64, nrows);

    // stage col indices (block-cooperative)
    const int eb1 = rp1[row0];
    const int cnt1 = min(rp1[rows_end] - eb1, cap);
    for (int i = t; i < cnt1; i += 256) sC1[i] = col1[eb1 + i];
    int eb2 = 0;
    if constexpr (HAS2) {
        eb2 = rp2[row0];
        const int cnt2 = min(rp2[rows_end] - eb2, cap);
        for (int i = t; i < cnt2; i += 256) sC2[i] = col2[eb2 + i];
    }
    __syncthreads();

    // Phase A: gather (quarter-wave per row, 4 rows each)
#pragma unroll
    for (int i = 0; i < 4; ++i) {
        const int rloc = w * 16 + q * 4 + i;
        const int gr = row0 + rloc;
        if (gr < nrows) {
            {
                const int s0 = rp1[gr], e1r = rp1[gr + 1];
                gather_row_h(src1h, col1, sC1, s0 - eb1, s0, e1r, c8, inv1[gr],
                             aggH1 + (size_t)rloc * AGS, cap);
            }
            if constexpr (HAS2) {
                const int s0 = rp2[gr], e1r = rp2[gr + 1];
                gather_row_h(src2h, col2, sC2, s0 - eb2, s0, e1r, c8, inv2[gr],
                             aggH2 + (size_t)rloc * AGS, cap);
            }
        }
    }

    // Phase B: MFMA. acc[nt] covers cols [nt*16, nt*16+16), rows w*16+q*4+reg.
    v4f acc[8];
#pragma unroll
    for (int nt = 0; nt < 8; ++nt) acc[nt] = (v4f){0.f, 0.f, 0.f, 0.f};

    // xdst term (fp16 mirror, no LDS dependency)
    const _Float16* xdrow = xdh + (size_t)(row0 + w * 16 + m) * 128;
#pragma unroll
    for (int kt = 0; kt < 4; ++kt) {
        h8 a = *(const h8*)(xdrow + kt * 32 + q * 8);
#pragma unroll
        for (int nt = 0; nt < 8; ++nt) {
            h8 b = *(const h8*)(WrTh + (size_t)(nt * 16 + m) * 128 + kt * 32 + q * 8);
            acc[nt] = __builtin_amdgcn_mfma_f32_16x16x32_f16(a, b, acc[nt], 0, 0, 0);
        }
    }
    __syncthreads();   // aggH writes visible / ordered

    const _Float16* arow1 = aggH1 + (size_t)(w * 16 + m) * AGS;
#pragma unroll
    for (int kt = 0; kt < 4; ++kt) {
        h8 a = *(const h8*)(arow1 + kt * 32 + q * 8);
#pragma unroll
        for (int nt = 0; nt < 8; ++nt) {
            h8 b = *(const h8*)(Wl1T + (size_t)(nt * 16 + m) * 128 + kt * 32 + q * 8);
            acc[nt] = __builtin_amdgcn_mfma_f32_16x16x32_f16(a, b, acc[nt], 0, 0, 0);
        }
    }
    if constexpr (HAS2) {
        const _Float16* arow2 = aggH2 + (size_t)(w * 16 + m) * AGS;
#pragma unroll
        for (int kt = 0; kt < 4; ++kt) {
            h8 a = *(const h8*)(arow2 + kt * 32 + q * 8);
#pragma unroll
            for (int nt = 0; nt < 8; ++nt) {
                h8 b = *(const h8*)(Wl2T + (size_t)(nt * 16 + m) * 128 + kt * 32 + q * 8);
                acc[nt] = __builtin_amdgcn_mfma_f32_16x16x32_f16(a, b, acc[nt], 0, 0, 0);
            }
        }
    }
    __syncthreads();   // all agg reads done before hbuf (aliased) overwrites

    // acc -> hbuf (layout transform for coalesced epilogue)
#pragma unroll
    for (int nt = 0; nt < 8; ++nt)
#pragma unroll
        for (int r = 0; r < 4; ++r)
            hbuf[(size_t)(w * 16 + q * 4 + r) * HBS + nt * 16 + m] = acc[nt][r];
    __syncthreads();

    // Phase C: bias + LayerNorm + ReLU + fp32 residual; fp32 + fp16 mirror stores
    v4f bg0 = *(const v4f*)&bl1[c8];
    v4f bg1 = *(const v4f*)&bl1[c8 + 4];
    if constexpr (HAS2) {
        bg0 += *(const v4f*)&bl2[c8];
        bg1 += *(const v4f*)&bl2[c8 + 4];
    }
    v4f g0 = *(const v4f*)&g[c8], g1 = *(const v4f*)&g[c8 + 4];
    v4f lb0 = *(const v4f*)&bln[c8], lb1 = *(const v4f*)&bln[c8 + 4];
#pragma unroll
    for (int i = 0; i < 4; ++i) {
        const int rloc = w * 16 + q * 4 + i;
        const int gr = row0 + rloc;
        if (gr >= nrows) continue;
        v4f h0 = *(const v4f*)&hbuf[(size_t)rloc * HBS + c8] + bg0;
        v4f h1 = *(const v4f*)&hbuf[(size_t)rloc * HBS + c8 + 4] + bg1;
        float part = h0.x + h0.y + h0.z + h0.w + h1.x + h1.y + h1.z + h1.w;
        float mean = qsum16(part) * (1.0f / 128.0f);
        v4f d0 = h0 - mean, d1 = h1 - mean;
        float vp = d0.x * d0.x + d0.y * d0.y + d0.z * d0.z + d0.w * d0.w +
                   d1.x * d1.x + d1.y * d1.y + d1.z * d1.z + d1.w * d1.w;
        float var = qsum16(vp) * (1.0f / 128.0f);
        float rs = rsqrtf(var + EPS);
        v4f x0 = *(const v4f*)&xdst[(size_t)gr * 128 + c8];
        v4f x1 = *(const v4f*)&xdst[(size_t)gr * 128 + c8 + 4];
        v4f y0, y1;
#pragma unroll
        for (int e = 0; e < 4; ++e) {
            y0[e] = fmaxf(d0[e] * rs * g0[e] + lb0[e], 0.f) + x0[e];
            y1[e] = fmaxf(d1[e] * rs * g1[e] + lb1[e], 0.f) + x1[e];
        }
        *(v4f*)&out[(size_t)gr * 128 + c8] = y0;
        *(v4f*)&out[(size_t)gr * 128 + c8 + 4] = y1;
        h8 oh;
#pragma unroll
        for (int e = 0; e < 4; ++e) {
            oh[e] = (_Float16)y0[e];
            oh[4 + e] = (_Float16)y1[e];
        }
        *(h8*)&out_h[(size_t)gr * 128 + c8] = oh;
    }
}

struct TrvParams {
    const float* xdst; float* out; _Float16* out_h; const _Float16* xdh;
    const _Float16* src1h; const int* rp1; const int* col1; const float* inv1;
    const _Float16* Wl1T; const float* bl1;
    const _Float16* src2h; const int* rp2; const int* col2; const float* inv2;
    const _Float16* Wl2T; const float* bl2;
    const _Float16* WrTh; const float* g; const float* bln;
};

struct UpdParams {
    const float* xdst; float* out; _Float16* out_h; const _Float16* xdh;
    const _Float16* srch; const int* rp; const int* col; const float* inv;
    const _Float16* WlT; const float* bl; const _Float16* WrT;
    const float* g; const float* bln;
    int nrows;
};

// Fused per-layer kernel: blocks [0,nbT) travel, [nbT,nbT+nbU) user, rest visit.
// All three are data-independent within a launch: gathers read [cur] mirrors
// (written by previous launch), epilogues write [nxt] mirrors + block-row-local
// fp32 masters. LDS = aggH 2x17408 (hbuf aliases) + 8192 col stage = 43008.
__global__ __launch_bounds__(256, 3) void layer_mfma(TrvParams T, UpdParams U, UpdParams V,
                                                     int nbT, int nbU) {
    __shared__ __align__(16) char smem[34816 + 8192];
    int b = blockIdx.x;
    if (b < nbT) {
        _Float16* aggH1 = (_Float16*)smem;
        _Float16* aggH2 = (_Float16*)(smem + 17408);
        float* hbuf = (float*)smem;
        int* sC1 = (int*)(smem + 34816);
        int* sC2 = sC1 + 1024;
        sage_mfma_body<1>(b * 64, NT, T.xdst, T.out, T.out_h, T.xdh,
                          T.src1h, T.rp1, T.col1, T.inv1, T.Wl1T, T.bl1,
                          T.src2h, T.rp2, T.col2, T.inv2, T.Wl2T, T.bl2,
                          T.WrTh, T.g, T.bln, aggH1, aggH2, hbuf, sC1, sC2, 1024);
    } else {
        b -= nbT;
        const bool isU = b < nbU;
        const UpdParams& P = isU ? U : V;
        const int row0 = (isU ? b : b - nbU) * 64;
        _Float16* aggH1 = (_Float16*)smem;
        float* hbuf = (float*)smem;
        int* sC1 = (int*)(smem + 34816);
        sage_mfma_body<0>(row0, P.nrows, P.xdst, P.out, P.out_h, P.xdh,
                          P.srch, P.rp, P.col, P.inv, P.WlT, P.bl,
                          nullptr, nullptr, nullptr, nullptr, nullptr, nullptr,
                          P.WrT, P.g, P.bln, aggH1, nullptr, hbuf, sC1, nullptr, 2048);
    }
}

// ---------------- generic Y[n x 128] = act(LN?(X[n x K]) @ W + b), optional fp16 mirror ----------------

template <int K, bool LN_IN, bool RELU, bool MIRROR>
__global__ __launch_bounds__(256) void gemm_kernel(const float* __restrict__ X,
                                                   const float* __restrict__ W,
                                                   const float* __restrict__ bias,
                                                   float* __restrict__ Y,
                                                   _Float16* __restrict__ Yh,
                                                   const float* __restrict__ g,
                                                   const float* __restrict__ bln) {
    static_assert(!LN_IN || K == 128, "LN input requires K==128");
    __shared__ __align__(16) float As[16 * K];
    const int t = threadIdx.x;
    const size_t row0 = (size_t)blockIdx.x * 16;

    for (int idx = t; idx < 16 * K; idx += 256) As[idx] = X[row0 * K + idx];
    __syncthreads();

    if (LN_IN) {
        const int w = t >> 6, l = t & 63;
        for (int qq = 0; qq < 4; ++qq) {
            const int r = w * 4 + qq;
            float a0 = As[r * K + l], a1 = As[r * K + 64 + l];
            float mm = wave_sum(a0 + a1) * (1.0f / 128.0f);
            float d0 = a0 - mm, d1 = a1 - mm;
            float var = wave_sum(d0 * d0 + d1 * d1) * (1.0f / 128.0f);
            float rs = rsqrtf(var + EPS);
            As[r * K + l] = d0 * rs * g[l] + bln[l];
            As[r * K + 64 + l] = d1 * rs * g[64 + l] + bln[64 + l];
        }
        __syncthreads();
    }

    const int c0 = (t & 31) * 4;
    const int r0 = (t >> 5) * 2;
    v4f b4 = *(const v4f*)&bias[c0];
    v4f acc0 = b4, acc1 = b4;
#pragma unroll 4
    for (int k = 0; k < K; k += 4) {
        v4f a0 = *(const v4f*)&As[r0 * K + k];
        v4f a1 = *(const v4f*)&As[(r0 + 1) * K + k];
        v4f w0 = *(const v4f*)&W[(size_t)(k + 0) * HD + c0];
        v4f w1 = *(const v4f*)&W[(size_t)(k + 1) * HD + c0];
        v4f w2 = *(const v4f*)&W[(size_t)(k + 2) * HD + c0];
        v4f w3 = *(const v4f*)&W[(size_t)(k + 3) * HD + c0];
        acc0 += a0.x * w0 + a0.y * w1 + a0.z * w2 + a0.w * w3;
        acc1 += a1.x * w0 + a1.y * w1 + a1.z * w2 + a1.w * w3;
    }
    if (RELU) {
#pragma unroll
        for (int i = 0; i < 4; ++i) {
            acc0[i] = fmaxf(acc0[i], 0.0f);
            acc1[i] = fmaxf(acc1[i], 0.0f);
        }
    }
    *(v4f*)&Y[(row0 + r0) * HD + c0] = acc0;
    *(v4f*)&Y[(row0 + r0 + 1) * HD + c0] = acc1;
    if (MIRROR) {
        h4 m0, m1;
#pragma unroll
        for (int i = 0; i < 4; ++i) {
            m0[i] = (_Float16)acc0[i];
            m1[i] = (_Float16)acc1[i];
        }
        *(h4*)&Yh[(row0 + r0) * HD + c0] = m0;
        *(h4*)&Yh[(row0 + r0 + 1) * HD + c0] = m1;
    }
}

// ---------------- attention-gate weight folding ----------------

__global__ __launch_bounds__(128) void fold_kernel(const float* __restrict__ Wv,
                                                   const float* __restrict__ bv,
                                                   const float* __restrict__ Wo,
                                                   const float* __restrict__ bo,
                                                   float* __restrict__ Wvo,
                                                   float* __restrict__ bvo) {
    const int c = threadIdx.x;
    const int r = blockIdx.x;
    if (r < 128) {
        float s = 0.f;
        for (int k = 0; k < 128; ++k) s += Wv[r * 128 + k] * Wo[k * 128 + c];
        Wvo[r * 128 + c] = s;
    } else {
        float s = bo[c];
        for (int k = 0; k < 128; ++k) s += bv[k] * Wo[k * 128 + c];
        bvo[c] = s;
    }
}

// ---------------- out[r] = dot(z[r], w2) + b2 ----------------

__global__ __launch_bounds__(256) void dot_kernel(const float* __restrict__ Z,
                                                  const float* __restrict__ w2,
                                                  const float* __restrict__ b2,
                                                  float* __restrict__ out, int n) {
    const int w = threadIdx.x >> 6, l = threadIdx.x & 63;
    const size_t row = (size_t)blockIdx.x * 4 + w;
    if (row < (size_t)n) {
        float v = Z[row * 128 + l] * w2[l] + Z[row * 128 + 64 + l] * w2[64 + l];
        v = wave_sum(v);
        if (l == 0) out[row] = v + b2[0];
    }
}

}  // namespace

extern "C" void kernel_launch(void* const* d_in, const int* in_sizes, int n_in,
                              void* d_out, int out_size, void* d_ws, size_t ws_size,
                              hipStream_t stream) {
    const float* x_user     = (const float*)d_in[0];
    const float* x_travel   = (const float*)d_in[1];
    float*       xv         = (float*)d_in[2];   // updated in place (harness restores inputs)
    const float* W_in_user  = (const float*)d_in[3];
    const float* b_in_user  = (const float*)d_in[4];
    const float* W_in_travel= (const float*)d_in[5];
    const float* b_in_travel= (const float*)d_in[6];
    const float* Wl         = (const float*)d_in[7];
    const float* bl         = (const float*)d_in[8];
    const float* Wr         = (const float*)d_in[9];
    const float* ln_g       = (const float*)d_in[10];
    const float* ln_b       = (const float*)d_in[11];
    // inputs 12..24: expert MLPs (dead) + attn_query/Wq/bq/Wk/bk (dead)
    const float* Wv_        = (const float*)d_in[25];
    const float* bv_        = (const float*)d_in[26];
    const float* Wo_        = (const float*)d_in[27];
    const float* bo_        = (const float*)d_in[28];
    const float* f_ln_g     = (const float*)d_in[29];
    const float* f_ln_b     = (const float*)d_in[30];
    const float* f_W1       = (const float*)d_in[31];
    const float* f_b1       = (const float*)d_in[32];
    const float* f_W2       = (const float*)d_in[33];
    const float* f_b2       = (const float*)d_in[34];
    const int*   ei_ut      = (const int*)d_in[35];
    const int*   ei_tu      = (const int*)d_in[36];
    const int*   ei_tv      = (const int*)d_in[37];
    const int*   ei_vt      = (const int*)d_in[38];
    const int E = in_sizes[35] / 2;

    // ---- workspace layout: ~105 MB base, ~136 MB with full mirror ping-pong ----
    constexpr size_t FUSED_NEED = (size_t)140 << 20;   // conservative: > exact 136 MB
    const bool fused = ws_size >= FUSED_NEED;

    char* wsb = (char*)d_ws;
    size_t off = 0;
    auto alloc = [&](size_t bytes) -> void* {
        off = (off + 511) & ~(size_t)511;
        void* p = wsb + off;
        off += bytes;
        return p;
    };
    float* xu = (float*)alloc((size_t)NU * HD * 4);
    float* xt = (float*)alloc((size_t)NT * HD * 4);
    // mirror region: first 4 buffers span 56.3 MB contiguous -> reused as the
    // NV x 128 fp32 attn buffer (51.2 MB) at head time (all mirrors dead then)
    _Float16* xu_h[2];
    _Float16* xv_h[2];
    _Float16* xt_h[2];
    xu_h[0] = (_Float16*)alloc((size_t)NUP * HD * 2);
    xv_h[0] = (_Float16*)alloc((size_t)NVP * HD * 2);
    xt_h[0] = (_Float16*)alloc((size_t)NTP * HD * 2);
    xt_h[1] = (_Float16*)alloc((size_t)NTP * HD * 2);
    if (fused) {
        xu_h[1] = (_Float16*)alloc((size_t)NUP * HD * 2);
        xv_h[1] = (_Float16*)alloc((size_t)NVP * HD * 2);
    } else {
        xu_h[1] = xu_h[0];   // sequential mode: travel reads before uv rewrites
        xv_h[1] = xv_h[0];
    }
    _Float16* WT = (_Float16*)alloc((size_t)LAYERS * 7 * 16384 * 2);
    float* Wvo = (float*)alloc(128 * 128 * 4);
    float* bvo = (float*)alloc(128 * 4);
    int* part = (int*)alloc(4 * 64 * 4);

    const int ndst[4] = {NU, NT, NT, NV};  // tu, ut, vt, tv
    int* cur4 = (int*)alloc((size_t)(NU + NT + NT + NV) * 4);
    int *rp[4], *colb[4];
    float* invb[4];
    int* cur[4];
    {
        int coff = 0;
        for (int i = 0; i < 4; ++i) {
            cur[i] = cur4 + coff;
            coff += ndst[i];
            rp[i]   = (int*)alloc((size_t)(ndst[i] + 1) * 4);
            colb[i] = (int*)alloc((size_t)E * 4);
            invb[i] = (float*)alloc((size_t)ndst[i] * 4);
        }
    }

    // ---- batched CSR build (XCD-residue-partitioned hist/scatter + hierarchical scan) ----
    hipMemsetAsync(cur4, 0, (size_t)(NU + NT + NT + NV) * 4, stream);
    CsrJobs J;
    J.j[0] = { ei_tu, ei_tu + E, cur[0], rp[0], colb[0], invb[0], NU };
    J.j[1] = { ei_ut, ei_ut + E, cur[1], rp[1], colb[1], invb[1], NT };
    J.j[2] = { ei_vt, ei_vt + E, cur[2], rp[2], colb[2], invb[2], NT };
    J.j[3] = { ei_tv, ei_tv + E, cur[3], rp[3], colb[3], invb[3], NV };
    const int nbPerC = (E + ECH - 1) / ECH;
    hist_all_kernel<<<4 * nbPerC * 8, 256, 0, stream>>>(J, E, nbPerC);
    csr_psum_kernel<<<4 * 64, 256, 0, stream>>>(J, part);
    csr_pscan_kernel<<<4, 64, 0, stream>>>(part);
    csr_scan_kernel<<<4 * 64, 256, 0, stream>>>(J, part);
    scatter_all_kernel<<<4 * nbPerC * 8, 256, 0, stream>>>(J, E, nbPerC);

    // ---- weight transpose+cast (fp16 W^T) ----
    tw_kernel<<<LAYERS * 7, 256, 0, stream>>>(Wl, Wr, WT);

    // ---- input projections (+ fp16 mirrors) ----
    gemm_kernel<64, false, false, true><<<NU / 16, 256, 0, stream>>>(
        x_user, W_in_user, b_in_user, xu, xu_h[0], nullptr, nullptr);
    gemm_kernel<32, false, false, true><<<NT / 16, 256, 0, stream>>>(
        x_travel, W_in_travel, b_in_travel, xt, xt_h[0], nullptr, nullptr);
    cast_kernel<<<(NV * HD / 4 + 255) / 256, 256, 0, stream>>>(xv, xv_h[0], NV * HD / 4);

    // ---- 8 hetero-SAGE layers ----
    const int nbU = (NU + 63) / 64;   // 313
    const int nbV = (NV + 63) / 64;   // 1563
    const int nbT = (NT + 63) / 64;   // 782
    for (int i = 0; i < LAYERS; ++i) {
        const _Float16* WTl = WT + (size_t)i * 7 * 16384;
        const float* bl_i = bl + (size_t)i * 4 * 128;
        const float* g_i  = ln_g + (size_t)i * 3 * 128;
        const float* b_i  = ln_b + (size_t)i * 3 * 128;
        const int c = i & 1, nx = c ^ 1;
        // travel: agg(xu_h[c] via ut, Wl0) + agg(xv_h[c] via vt, Wl3) + xt@(Wr0+Wr3)
        TrvParams T = { xt, xt, xt_h[nx], xt_h[c],
                        xu_h[c], rp[1], colb[1], invb[1], WTl + 0 * 16384, bl_i + 0 * 128,
                        xv_h[c], rp[2], colb[2], invb[2], WTl + 3 * 16384, bl_i + 3 * 128,
                        WTl + 4 * 16384, g_i + 1 * 128, b_i + 1 * 128 };
        UpdParams U = { xu, xu, xu_h[nx], xu_h[c], xt_h[c], rp[0], colb[0], invb[0],
                        WTl + 1 * 16384, bl_i + 1 * 128, WTl + 5 * 16384,
                        g_i + 0 * 128, b_i + 0 * 128, NU };
        UpdParams V = { xv, xv, xv_h[nx], xv_h[c], xt_h[c], rp[3], colb[3], invb[3],
                        WTl + 2 * 16384, bl_i + 2 * 128, WTl + 6 * 16384,
                        g_i + 2 * 128, b_i + 2 * 128, NV };
        if (fused) {
            layer_mfma<<<nbT + nbU + nbV, 256, 0, stream>>>(T, U, V, nbT, nbU);
        } else {
            // sequential: travel reads xu_h/xv_h before uv rewrites them in place
            layer_mfma<<<nbT, 256, 0, stream>>>(T, U, V, nbT, nbU);
            layer_mfma<<<nbU + nbV, 256, 0, stream>>>(T, U, V, 0, nbU);
        }
    }

    // ---- head ----
    fold_kernel<<<129, 128, 0, stream>>>(Wv_, bv_, Wo_, bo_, Wvo, bvo);
    float* attn = (float*)xu_h[0];  // 56.3 MB contiguous mirror region, dead at head
    gemm_kernel<128, false, false, false><<<NV / 16, 256, 0, stream>>>(
        xv, Wvo, bvo, attn, nullptr, nullptr, nullptr);
    gemm_kernel<128, true, true, false><<<NV / 16, 256, 0, stream>>>(
        attn, f_W1, f_b1, attn, nullptr, f_ln_g, f_ln_b);
    dot_kernel<<<NV / 4, 256, 0, stream>>>(attn, f_W2, f_b2, (float*)d_out, NV);
}